// Round 5
// baseline (280.744 us; speedup 1.0000x reference)
//
#include <hip/hip_runtime.h>
#include <stdint.h>

#define NB_LAYERS 4
#define KSIZE 5
#define BSZ 8
#define LIN 2048
#define LSEQ 2049
#define CCH 32
#define HCH 16
#define MROWS (BSZ*LSEQ)          // 16392
#define NTILES ((MROWS+15)/16)    // 1025
#define KDIM 576                  // 512 (h*c) + 32 (k3b block) + 32 (skip block)
#define NEG 0.1f
#define BNEPS 1e-5f
#define NWAVEMAX 256              // (BSZ*LIN)/64
#define GRID 205
#define BLOCK 320                 // 5 waves * 205 blocks = 1025 waves = NTILES exactly
#define NWAVES (BLOCK/64)
#define NTHREADS (GRID*BLOCK)     // 65600

typedef _Float16 h2v __attribute__((ext_vector_type(2)));
typedef _Float16 h8v __attribute__((ext_vector_type(8)));
typedef float    f4v __attribute__((ext_vector_type(4)));

union H8 { h8v v; h2v h[4]; };

static __device__ __forceinline__ h2v mkh2(float a, float b) {
  h2v r; r[0] = (_Float16)a; r[1] = (_Float16)b; return r;
}

struct CParams {
  const float* etimes; const int* types; const float* emb;
  const float* k1W; const float* k1b; const float* k2W; const float* k2b;
  const float* k3W; const float* k3b; const float* skipW;
  const float* gamma; const float* beta;
  float* enc_a; float* enc_b; float* stats; int* wavemax;
  int* barmem;            // [0]=cnt, [1]=sense (memset to 0 before launch)
  _Float16* Wt; float* out;
};

// ---- lightweight grid barrier: one atomic + LLC spin, single fence each side ----
// (replaces cg::grid.sync(): R1 showed ~55us/barrier from cg's sleep-backoff spin)
static __device__ __forceinline__ void gbar(int* cnt, int* sense, int epoch) {
  __syncthreads();                 // block stores drained (compiler emits vmcnt(0))
  if (threadIdx.x == 0) {
    __threadfence();               // release: push this XCD's dirty L2 to LLC
    int prev = __hip_atomic_fetch_add(cnt, 1, __ATOMIC_ACQ_REL, __HIP_MEMORY_SCOPE_AGENT);
    if (prev == GRID - 1) {
      __hip_atomic_store(cnt, 0, __ATOMIC_RELAXED, __HIP_MEMORY_SCOPE_AGENT);
      __hip_atomic_store(sense, epoch, __ATOMIC_RELEASE, __HIP_MEMORY_SCOPE_AGENT);
    } else {
      while (__hip_atomic_load(sense, __ATOMIC_ACQUIRE, __HIP_MEMORY_SCOPE_AGENT) < epoch)
        __builtin_amdgcn_s_sleep(1);
    }
    __threadfence();               // acquire: invalidate stale L1/L2 before re-reading
  }
  __syncthreads();
}

// ---------------- fused cont-conv layer (R3 body, verbatim logic) ----------------
// MODE 0: layer-0, embedding lookup fused at gather time.
// MODE 1: layers 1-3, previous layer's BN+leaky fused into gathers.
template<int MODE>
static __device__ __forceinline__ void conv_layer(
    const CParams& P, int bid,
    const float* __restrict__ enc_in, float* __restrict__ enc_out,
    const float* __restrict__ k1Wp, const float* __restrict__ k1bp,
    const float* __restrict__ k2Wp, const float* __restrict__ k2bp,
    const _Float16* __restrict__ WtL,
    const float* __restrict__ stats_prev, float* __restrict__ stats_out,
    const float* __restrict__ gamma_prev, const float* __restrict__ beta_prev,
    int dil, float* sW, h8v* swh, float* sst)
{
  const int tid  = threadIdx.x;
  const int lane = tid & 63;
  const int wv   = tid >> 6;
  const int m    = lane & 15;     // A-frag row within tile / B-frag col n
  const int q    = lane >> 4;     // quad: k-subchunk + feat channels q*8..q*8+7
  const float* etimes = P.etimes;

  // ---- stage MLP weights + zero stats scratch ----
  if (tid < 64) sst[tid] = 0.f;
  if (tid < 16) { sW[tid] = k1Wp[tid]; sW[16 + tid] = k1bp[tid]; sW[32 + tid] = k2bp[tid]; }
  if (tid >= 64) sW[48 + tid - 64] = k2Wp[tid - 64];   // 256 entries, threads 64..319
  __syncthreads();

  // BN of previous layer, fused into loads: x -> leaky(x*sc + ob)
  float sc8[8], ob8[8];
  if (MODE == 1) {
    const float inv = 1.f / (float)MROWS;
#pragma unroll
    for (int j = 0; j < 8; j++) {
      int c = q * 8 + j;
      float mu = stats_prev[c] * inv;
      float var = stats_prev[32 + c] * inv - mu * mu;
      float sc = gamma_prev[c] * rsqrtf(var + BNEPS);
      sc8[j] = sc; ob8[j] = beta_prev[c] - mu * sc;
    }
  }

  const _Float16* wb0 = WtL + m * KDIM + q * 8;
  const _Float16* wb1 = WtL + (m + 16) * KDIM + q * 8;

  const int tile = bid * NWAVES + wv;   // exactly one tile per wave, 1025 total
  int row = tile * 16 + m;
  bool rvalid = row < MROWS;
  int rowc = min(row, MROWS - 1);
  int b = rowc / LSEQ, pos = rowc % LSEQ;
  float t_l = (pos == 0) ? 0.f : etimes[b * LIN + pos - 1];
  bool mask_l = rvalid && (t_l != 0.f);

  // BOS embedding row index (only conv0, only waves containing a pos==0 row)
  int bosv = 0;
  if (MODE == 0) {
    if (__ballot(pos == 0)) {
      const int4* wm = (const int4*)P.wavemax;
      int mx = 0;
#pragma unroll 4
      for (int i = 0; i < NWAVEMAX / 4; i++) {
        int4 v = wm[i];
        mx = max(mx, max(max(v.x, v.y), max(v.z, v.w)));
      }
      bosv = mx + 1;
    }
  }

  // ---- phase G: prefetch all gather data, then transform ----
  int jcs[KSIZE]; float tjv[KSIZE];
#pragma unroll
  for (int tap = 0; tap < KSIZE; tap++) {
    int j = pos - tap * dil;
    int jc = max(j, 0); jcs[tap] = jc;
    tjv[tap] = (jc == 0) ? 0.f : etimes[b * LIN + jc - 1];
  }
  float4 fa[KSIZE], fbv[KSIZE];
  int tts[KSIZE];
  if (MODE == 0) {
#pragma unroll
    for (int tap = 0; tap < KSIZE; tap++) {
      int jc = jcs[tap];
      tts[tap] = (jc > 0) ? P.types[b * LIN + jc - 1] : ((tap == 0) ? bosv : 0);
    }
#pragma unroll
    for (int tap = 0; tap < KSIZE; tap++) {
      const float* ep = P.emb + tts[tap] * CCH + q * 8;
      fa[tap] = *(const float4*)ep; fbv[tap] = *(const float4*)(ep + 4);
    }
  } else {
#pragma unroll
    for (int tap = 0; tap < KSIZE; tap++) {
      const float* fp = enc_in + (b * LSEQ + jcs[tap]) * CCH + q * 8;
      fa[tap] = *(const float4*)fp; fbv[tap] = *(const float4*)(fp + 4);
    }
  }

  h2v fh[KSIZE][4];
  h2v fself[4];
  float Fb[8];
#pragma unroll
  for (int jj = 0; jj < 8; jj++) Fb[jj] = 0.f;

#pragma unroll
  for (int tap = 0; tap < KSIZE; tap++) {
    bool gm = mask_l && (pos - tap * dil >= 0) && (tjv[tap] != 0.f);
    float fv[8] = {fa[tap].x, fa[tap].y, fa[tap].z, fa[tap].w,
                   fbv[tap].x, fbv[tap].y, fbv[tap].z, fbv[tap].w};
    if (MODE == 0) {
      float zf = (tts[tap] != 0) ? 1.f : 0.f;
#pragma unroll
      for (int jj = 0; jj < 8; jj++) fv[jj] *= zf;
    } else {
#pragma unroll
      for (int jj = 0; jj < 8; jj++) {
        float x = fmaf(fv[jj], sc8[jj], ob8[jj]);
        fv[jj] = fmaxf(x, NEG * x);
      }
    }
    if (tap == 0) {
      float rv = rvalid ? 1.f : 0.f;
#pragma unroll
      for (int p2 = 0; p2 < 4; p2++) fself[p2] = mkh2(fv[2*p2] * rv, fv[2*p2+1] * rv);
    }
    float g = gm ? 1.f : 0.f;
#pragma unroll
    for (int jj = 0; jj < 8; jj++) Fb[jj] += g * fv[jj];
#pragma unroll
    for (int p2 = 0; p2 < 4; p2++) fh[tap][p2] = mkh2(fv[2*p2], fv[2*p2+1]);
  }

  // ---- phase M: 80 (row,tap) MLP jobs distributed over lanes ----
#pragma unroll
  for (int rep = 0; rep < 2; rep++) {
    const int jt = rep ? (KSIZE - 1) : (lane >> 4);
    const bool act = rep ? (lane < 16) : true;
    int j2 = pos - jt * dil;
    int jc2 = max(j2, 0);
    float tj2 = (jc2 == 0) ? 0.f : etimes[b * LIN + jc2 - 1];
    bool g2 = act && mask_l && (j2 >= 0) && (tj2 != 0.f);
    float dt = g2 ? (t_l - tj2) : 0.f;

    H8 w0, w1;
    if (__ballot(g2)) {
      const f4v* k1wv = (const f4v*)&sW[0];
      const f4v* k1bv = (const f4v*)&sW[16];
      const f4v* k2bv = (const f4v*)&sW[32];
      float h1[HCH], h2[HCH];
#pragma unroll
      for (int h4 = 0; h4 < 4; h4++) {
        f4v cw = k1wv[h4], cb = k1bv[h4], c2 = k2bv[h4];
#pragma unroll
        for (int r = 0; r < 4; r++) {
          float x = fmaf(dt, cw[r], cb[r]);
          h1[h4*4+r] = fmaxf(x, NEG * x);
          h2[h4*4+r] = c2[r];
        }
      }
#pragma unroll
      for (int hp = 0; hp < HCH; hp++) {
        float hv = h1[hp];
        const f4v* kk = (const f4v*)&sW[48 + hp * 16];
#pragma unroll
        for (int h4 = 0; h4 < 4; h4++) {
          f4v c = kk[h4];
#pragma unroll
          for (int r = 0; r < 4; r++) h2[h4*4+r] = fmaf(hv, c[r], h2[h4*4+r]);
        }
      }
      float g = g2 ? 1.f : 0.f;
#pragma unroll
      for (int p2 = 0; p2 < 4; p2++) {
        float a0 = h2[2*p2];     a0 = fmaxf(a0, NEG * a0) * g;
        float a1 = h2[2*p2+1];   a1 = fmaxf(a1, NEG * a1) * g;
        w0.h[p2] = mkh2(a0, a1);
        float b0 = h2[8+2*p2];   b0 = fmaxf(b0, NEG * b0) * g;
        float b1 = h2[8+2*p2+1]; b1 = fmaxf(b1, NEG * b1) * g;
        w1.h[p2] = mkh2(b0, b1);
      }
    } else {
#pragma unroll
      for (int p2 = 0; p2 < 4; p2++) { w0.h[p2] = mkh2(0.f, 0.f); w1.h[p2] = mkh2(0.f, 0.f); }
    }
    if (act) {
      int base = ((wv * KSIZE + jt) * 16 + m) * 2;
      swh[base] = w0.v; swh[base + 1] = w1.v;
    }
  }
  __syncthreads();

  // ---- phase U: read wh, pack A-frags, MFMA ----
  h2v wh[KSIZE][8];
#pragma unroll
  for (int tap = 0; tap < KSIZE; tap++) {
    int base = ((wv * KSIZE + tap) * 16 + m) * 2;
    H8 a0, a1; a0.v = swh[base]; a1.v = swh[base + 1];
#pragma unroll
    for (int p2 = 0; p2 < 4; p2++) { wh[tap][p2] = a0.h[p2]; wh[tap][4+p2] = a1.h[p2]; }
  }

  f4v aP = {0,0,0,0}, aQ = {0,0,0,0}, bP = {0,0,0,0}, bQ = {0,0,0,0};

#pragma unroll
  for (int ks = 0; ks < 16; ks++) {
    H8 bf0, bf1, af;
    bf0.v = *(const h8v*)(wb0 + ks * 32);
    bf1.v = *(const h8v*)(wb1 + ks * 32);
    h2v u0 = mkh2(0.f,0.f), u1 = mkh2(0.f,0.f), u2 = mkh2(0.f,0.f), u3 = mkh2(0.f,0.f);
#pragma unroll
    for (int tap = 0; tap < KSIZE; tap++) {
      _Float16 w = wh[tap][ks >> 1][ks & 1];
      h2v wd; wd[0] = w; wd[1] = w;
      u0 += wd * fh[tap][0];
      u1 += wd * fh[tap][1];
      u2 += wd * fh[tap][2];
      u3 += wd * fh[tap][3];
    }
    af.h[0] = u0; af.h[1] = u1; af.h[2] = u2; af.h[3] = u3;
    if (ks & 1) {
      aQ = __builtin_amdgcn_mfma_f32_16x16x32_f16(af.v, bf0.v, aQ, 0, 0, 0);
      bQ = __builtin_amdgcn_mfma_f32_16x16x32_f16(af.v, bf1.v, bQ, 0, 0, 0);
    } else {
      aP = __builtin_amdgcn_mfma_f32_16x16x32_f16(af.v, bf0.v, aP, 0, 0, 0);
      bP = __builtin_amdgcn_mfma_f32_16x16x32_f16(af.v, bf1.v, bP, 0, 0, 0);
    }
  }
  { // k3b block (k = 512..543)
    H8 bf0, bf1, af;
    bf0.v = *(const h8v*)(wb0 + 512);
    bf1.v = *(const h8v*)(wb1 + 512);
#pragma unroll
    for (int p2 = 0; p2 < 4; p2++) af.h[p2] = mkh2(Fb[2*p2], Fb[2*p2+1]);
    aP = __builtin_amdgcn_mfma_f32_16x16x32_f16(af.v, bf0.v, aP, 0, 0, 0);
    bP = __builtin_amdgcn_mfma_f32_16x16x32_f16(af.v, bf1.v, bP, 0, 0, 0);
  }
  { // skip block (k = 544..575)
    H8 bf0, bf1, af;
    bf0.v = *(const h8v*)(wb0 + 544);
    bf1.v = *(const h8v*)(wb1 + 544);
    af.h[0] = fself[0]; af.h[1] = fself[1]; af.h[2] = fself[2]; af.h[3] = fself[3];
    aQ = __builtin_amdgcn_mfma_f32_16x16x32_f16(af.v, bf0.v, aQ, 0, 0, 0);
    bQ = __builtin_amdgcn_mfma_f32_16x16x32_f16(af.v, bf1.v, bQ, 0, 0, 0);
  }
  f4v acc0 = aP + aQ;
  f4v acc1 = bP + bQ;

  // epilogue: store + BN stats.  D layout: col = lane&15, row = (lane>>4)*4 + r
  float s0 = 0.f, s1 = 0.f, s2 = 0.f, s3 = 0.f;
#pragma unroll
  for (int r = 0; r < 4; r++) {
    float v0 = acc0[r], v1 = acc1[r];
    s0 += v0; s1 += v0 * v0; s2 += v1; s3 += v1 * v1;
    int rd = tile * 16 + q * 4 + r;
    if (rd < MROWS) {
      enc_out[rd * CCH + m] = v0;
      enc_out[rd * CCH + 16 + m] = v1;
    }
  }
  s0 += __shfl_xor(s0, 16, 64); s0 += __shfl_xor(s0, 32, 64);
  s1 += __shfl_xor(s1, 16, 64); s1 += __shfl_xor(s1, 32, 64);
  s2 += __shfl_xor(s2, 16, 64); s2 += __shfl_xor(s2, 32, 64);
  s3 += __shfl_xor(s3, 16, 64); s3 += __shfl_xor(s3, 32, 64);
  if (q == 0) {
    atomicAdd(&sst[m], s0);
    atomicAdd(&sst[32 + m], s1);
    atomicAdd(&sst[16 + m], s2);
    atomicAdd(&sst[48 + m], s3);
  }
  __syncthreads();
  if (tid < 64) atomicAdd(&stats_out[tid], sst[tid]);
}

// ---------------- single cooperative kernel, custom barriers ----------------
__global__ __launch_bounds__(BLOCK, 1) void ccnn_kernel(CParams P) {
  __shared__ alignas(16) float sW[304];          // k1w[16] k1b[16] k2b[16] k2W[256]
  __shared__ h8v swh[NWAVES * KSIZE * 16 * 2];   // per-wave MLP results
  __shared__ float sst[64];

  const int tid = threadIdx.x;
  const int bid = blockIdx.x;
  const int gtid = bid * BLOCK + tid;
  int* cnt = P.barmem;
  int* sense = P.barmem + 1;

  // ---- phase 0: zero BN stats + per-wave type max + fp16 weight table ----
  if (bid == 0 && tid < NB_LAYERS * 64) P.stats[tid] = 0.f;
  if (gtid < BSZ * LIN) {
    int v = P.types[gtid];
#pragma unroll
    for (int off = 32; off; off >>= 1) v = max(v, __shfl_xor(v, off, 64));
    if ((tid & 63) == 0) P.wavemax[gtid >> 6] = v;
  }
  for (int id = gtid; id < NB_LAYERS * CCH * KDIM; id += NTHREADS) {
    int layer = id / (CCH * KDIM);
    int rem = id % (CCH * KDIM);
    int n = rem / KDIM;
    int k = rem % KDIM;
    float val;
    if (k < 512)      { int h = k >> 5, c = k & 31; val = P.k3W[layer*16384 + h*1024 + c*32 + n]; }
    else if (k < 544) { int c = k - 512;            val = P.k3b[layer*1024 + c*32 + n]; }
    else              { int c = k - 544;            val = P.skipW[layer*1024 + c*32 + n]; }
    P.Wt[id] = (_Float16)val;
  }
  gbar(cnt, sense, 1);

  // ---- 4 conv layers ----
  conv_layer<0>(P, bid, nullptr, P.enc_b,
      P.k1W, P.k1b, P.k2W, P.k2b, P.Wt,
      nullptr, P.stats, nullptr, nullptr, 1, sW, swh, sst);
  gbar(cnt, sense, 2);

  conv_layer<1>(P, bid, P.enc_b, P.enc_a,
      P.k1W + HCH, P.k1b + HCH, P.k2W + HCH*HCH, P.k2b + HCH,
      P.Wt + 1 * CCH * KDIM,
      P.stats, P.stats + 64, P.gamma, P.beta, 2, sW, swh, sst);
  gbar(cnt, sense, 3);

  conv_layer<1>(P, bid, P.enc_a, P.enc_b,
      P.k1W + 2*HCH, P.k1b + 2*HCH, P.k2W + 2*HCH*HCH, P.k2b + 2*HCH,
      P.Wt + 2 * CCH * KDIM,
      P.stats + 64, P.stats + 128, P.gamma + CCH, P.beta + CCH, 4, sW, swh, sst);
  gbar(cnt, sense, 4);

  conv_layer<1>(P, bid, P.enc_b, P.enc_a,
      P.k1W + 3*HCH, P.k1b + 3*HCH, P.k2W + 3*HCH*HCH, P.k2b + 3*HCH,
      P.Wt + 3 * CCH * KDIM,
      P.stats + 128, P.stats + 192, P.gamma + 2*CCH, P.beta + 2*CCH, 8, sW, swh, sst);
  gbar(cnt, sense, 5);

  // ---- final BN + leaky of layer 3 -> out ----
  {
    const float* st = P.stats + 3 * 64;
    const int c = gtid & 31;          // NTHREADS % 32 == 0 -> channel constant per thread
    const float inv = 1.f / (float)MROWS;
    float mu = st[c] * inv;
    float var = st[32 + c] * inv - mu * mu;
    float sc = P.gamma[3 * CCH + c] * rsqrtf(var + BNEPS);
    float ob = P.beta[3 * CCH + c] - mu * sc;
    for (int id = gtid; id < MROWS * CCH; id += NTHREADS) {
      float v = fmaf(P.enc_a[id], sc, ob);
      P.out[id] = fmaxf(v, NEG * v);
    }
  }
}

extern "C" void kernel_launch(void* const* d_in, const int* in_sizes, int n_in,
                              void* d_out, int out_size, void* d_ws, size_t ws_size,
                              hipStream_t stream) {
  (void)in_sizes; (void)n_in; (void)out_size; (void)ws_size;
  CParams p;
  p.etimes = (const float*)d_in[0];
  p.types  = (const int*)d_in[1];
  p.emb    = (const float*)d_in[2];
  p.k1W    = (const float*)d_in[3];
  p.k1b    = (const float*)d_in[4];
  p.k2W    = (const float*)d_in[5];
  p.k2b    = (const float*)d_in[6];
  p.k3W    = (const float*)d_in[7];
  p.k3b    = (const float*)d_in[8];
  p.skipW  = (const float*)d_in[9];
  // d_in[10] = skipb: BN-invariant, dropped
  p.gamma  = (const float*)d_in[11];
  p.beta   = (const float*)d_in[12];

  float* enc_a = (float*)d_ws;
  float* enc_b = enc_a + (size_t)MROWS * CCH;
  float* stats = enc_b + (size_t)MROWS * CCH;
  int* wavemax = (int*)(stats + NB_LAYERS * 64);
  int* barmem  = wavemax + NWAVEMAX;
  _Float16* Wt = (_Float16*)(((uintptr_t)(barmem + 4) + 255) & ~(uintptr_t)255);

  p.enc_a = enc_a; p.enc_b = enc_b; p.stats = stats; p.wavemax = wavemax;
  p.barmem = barmem; p.Wt = Wt; p.out = (float*)d_out;

  hipMemsetAsync(barmem, 0, 16, stream);   // cnt=0, sense=0 (workspace is poisoned)

  void* kargs[] = { (void*)&p };
  hipLaunchCooperativeKernel((const void*)ccnn_kernel, dim3(GRID), dim3(BLOCK),
                             kargs, 0, stream);
}

// Round 6
// 167.696 us; speedup vs baseline: 1.6741x; 1.6741x over previous
//
#include <hip/hip_runtime.h>
#include <stdint.h>

#define NB_LAYERS 4
#define KSIZE 5
#define BSZ 8
#define LIN 2048
#define LSEQ 2049
#define CCH 32
#define HCH 16
#define MROWS (BSZ*LSEQ)          // 16392
#define NTILES ((MROWS+15)/16)    // 1025
#define NEG 0.1f
#define BNEPS 1e-5f
#define GRID 257                  // 257*4 waves = 1028 tiles (1025 real, 3 dead->early-exit)
#define BLK 256
#define NFRAG 36                  // 32 K-frags + 2 k3b + 2 skip
#define WT_HALVES (NFRAG*64*8)    // 18432 fp16 per layer

typedef _Float16 h2v __attribute__((ext_vector_type(2)));
typedef _Float16 h8v __attribute__((ext_vector_type(8)));
typedef float    f4v __attribute__((ext_vector_type(4)));

union H8 { h8v v; h2v h[4]; };

static __device__ __forceinline__ h2v mkh2(float a, float b) {
  h2v r; r[0] = (_Float16)a; r[1] = (_Float16)b; return r;
}

// decode one source element of a layer's weight table -> (dest half-index, value)
// source linear g: [0,16384) k3W slice, [16384,17408) k3b, [17408,18432) skipW
// dest layout: frag f (0..35) * 512 + lane(q<<4|m) * 8 + half(0..7)
// -> B-frag reads are lane-consecutive 16B chunks: conflict-free in LDS, coalesced in global.
// (harness-verified in R4)
static __device__ __forceinline__ void wt_decode(
    int g, const float* __restrict__ k3Wl, const float* __restrict__ k3bl,
    const float* __restrict__ skipWl, int& halfidx, float& val) {
  int n, k;
  if (g < 16384)      { n = g & 31; int c = (g >> 5) & 31; int h = g >> 10; k = h * 32 + c; val = k3Wl[g]; }
  else if (g < 17408) { int g2 = g - 16384; n = g2 & 31; int c = g2 >> 5; k = 512 + c; val = k3bl[g2]; }
  else                { int g2 = g - 17408; n = g2 & 31; int c = g2 >> 5; k = 544 + c; val = skipWl[g2]; }
  int m = n & 15, a = n >> 4, qq = (k >> 3) & 3, hh = k & 7;
  int f = (k < 512) ? ((k >> 5) * 2 + a) : ((k < 544) ? (32 + a) : (34 + a));
  halfidx = f * 512 + ((qq << 4) | m) * 8 + hh;
}

// ---------------- fused cont-conv layer ----------------
// MODE 0 (conv0): prep fused — builds LDS B-frag table from fp32, writes global fp16
//   tables for layers 1-3, zeroes stats[1..3], inline BOS type-max, embedding fused
//   into gathers, BN stats out as per-block partials (no atomics, no pre-zero).
// MODE 1 (conv1-3): previous layer's BN+leaky fused into gathers (conv1 reduces
//   conv0's partials; conv2/3 read stats), B-frags read frag-linear from global
//   (coalesced), stats via atomics into memory zeroed by conv0.
template<int MODE>
__global__ __launch_bounds__(BLK) void conv_kernel(
    const float* __restrict__ enc_in,
    const int*   __restrict__ types,
    const float* __restrict__ emb,
    float* __restrict__ enc_out,
    const float* __restrict__ etimes,
    const float* __restrict__ k1Wp, const float* __restrict__ k1bp,
    const float* __restrict__ k2Wp, const float* __restrict__ k2bp,
    const float* __restrict__ k3W, const float* __restrict__ k3b,
    const float* __restrict__ skipW,
    _Float16* __restrict__ WtG,               // MODE0: write base (layers 1-3); MODE1: this layer's slice (read)
    const float* __restrict__ stats_prev,     // conv2/3
    const float* __restrict__ partials_prev,  // conv1
    float* __restrict__ stats_out,            // conv1..3 atomic dest
    float* __restrict__ partials_out,         // conv0
    float* __restrict__ stats_zero,           // conv0: 192 floats (stats[1..3])
    const float* __restrict__ gamma_prev, const float* __restrict__ beta_prev,
    int dil)
{
  __shared__ h8v Wl[(MODE == 0) ? (NFRAG * 64) : 1];   // 36 KB (conv0 only)
  __shared__ h8v swh[(BLK/64) * KSIZE * 16 * 2];       // per-wave MLP results
  __shared__ alignas(16) float sW[304];                // k1w[16] k1b[16] k2b[16] k2W[256]
  __shared__ float sst[64];
  __shared__ float sbn[64];

  const int tid  = threadIdx.x;
  const int lane = tid & 63;
  const int wv   = tid >> 6;
  const int m    = lane & 15;     // A-frag row within tile / B-frag col n
  const int q    = lane >> 4;     // quad: k-subchunk + feat channels q*8..q*8+7

  // ---- staging ----
  if (tid < 64) sst[tid] = 0.f;
  if (tid < 16) { sW[tid] = k1Wp[tid]; sW[16 + tid] = k1bp[tid]; sW[32 + tid] = k2bp[tid]; }
  sW[48 + tid] = k2Wp[tid];                            // all 256 entries

  if (MODE == 0) {
    if (blockIdx.x == 0 && tid < 192) stats_zero[tid] = 0.f;
    // layer-0 B-frag table into LDS: coalesced fp32 reads, scattered ds_write_b16
    for (int g = tid; g < WT_HALVES; g += BLK) {
      int hi; float val;
      wt_decode(g, k3W, k3b, skipW, hi, val);
      ((_Float16*)Wl)[hi] = (_Float16)val;
    }
    // layers 1-3 fp16 tables to global: one element per thread grid-wide
    int id2 = blockIdx.x * BLK + tid;
    if (id2 < 3 * WT_HALVES) {
      int layer = 1 + id2 / WT_HALVES;
      int g = id2 - (layer - 1) * WT_HALVES;
      int hi; float val;
      wt_decode(g, k3W + layer * 16384, k3b + layer * 1024, skipW + layer * 1024, hi, val);
      WtG[(layer - 1) * WT_HALVES + hi] = (_Float16)val;
    }
  } else {
    if (partials_prev && tid < 64) sbn[tid] = 0.f;
  }
  __syncthreads();

  // conv1 only: reduce conv0's per-block stat partials (coalesced, 4-way LDS atomic depth)
  if (MODE == 1 && partials_prev) {
    float v = 0.f;
    for (int i = tid; i < GRID * 64; i += BLK) v += partials_prev[i];
    atomicAdd(&sbn[tid & 63], v);
    __syncthreads();
  }

  // BN of previous layer, fused into loads: x -> leaky(x*sc + ob)
  float sc8[8], ob8[8];
  if (MODE == 1) {
    const float inv = 1.f / (float)MROWS;
#pragma unroll
    for (int j = 0; j < 8; j++) {
      int c = q * 8 + j;
      float s1 = partials_prev ? sbn[c]      : stats_prev[c];
      float s2 = partials_prev ? sbn[32 + c] : stats_prev[32 + c];
      float mu = s1 * inv;
      float var = s2 * inv - mu * mu;
      float sc = gamma_prev[c] * rsqrtf(var + BNEPS);
      sc8[j] = sc; ob8[j] = beta_prev[c] - mu * sc;
    }
  }

  const int tile = blockIdx.x * (BLK / 64) + wv;       // one tile per wave
  const bool deadtile = (tile * 16 >= MROWS);          // tiles 1025..1027: fully dead

  if (!deadtile) {
    int row = tile * 16 + m;
    bool rvalid = row < MROWS;
    int rowc = min(row, MROWS - 1);
    int b = rowc / LSEQ, pos = rowc % LSEQ;
    float t_l = (pos == 0) ? 0.f : etimes[b * LIN + pos - 1];
    bool mask_l = rvalid && (t_l != 0.f);

    // BOS embedding index: inline int4 scan (only the 8 waves containing a pos==0 row)
    int bosv = 0;
    if (MODE == 0) {
      if (__ballot(pos == 0)) {
        const int4* tp = (const int4*)types;
        int mx = 0;
#pragma unroll 4
        for (int i = lane; i < (BSZ * LIN) / 4; i += 64) {
          int4 v = tp[i];
          mx = max(mx, max(max(v.x, v.y), max(v.z, v.w)));
        }
#pragma unroll
        for (int off = 32; off; off >>= 1) mx = max(mx, __shfl_xor(mx, off, 64));
        bosv = mx + 1;
      }
    }

    // ---- phase G: prefetch all gather data, then transform ----
    int jcs[KSIZE]; float tjv[KSIZE];
#pragma unroll
    for (int tap = 0; tap < KSIZE; tap++) {
      int j = pos - tap * dil;
      int jc = max(j, 0); jcs[tap] = jc;
      tjv[tap] = (jc == 0) ? 0.f : etimes[b * LIN + jc - 1];
    }
    float4 fa[KSIZE], fbv[KSIZE];
    int tts[KSIZE];
    if (MODE == 0) {
#pragma unroll
      for (int tap = 0; tap < KSIZE; tap++) {
        int jc = jcs[tap];
        tts[tap] = (jc > 0) ? types[b * LIN + jc - 1] : ((tap == 0) ? bosv : 0);
      }
#pragma unroll
      for (int tap = 0; tap < KSIZE; tap++) {
        const float* ep = emb + tts[tap] * CCH + q * 8;
        fa[tap] = *(const float4*)ep; fbv[tap] = *(const float4*)(ep + 4);
      }
    } else {
#pragma unroll
      for (int tap = 0; tap < KSIZE; tap++) {
        const float* fp = enc_in + (b * LSEQ + jcs[tap]) * CCH + q * 8;
        fa[tap] = *(const float4*)fp; fbv[tap] = *(const float4*)(fp + 4);
      }
    }

    h2v fh[KSIZE][4];
    h2v fself[4];
    float Fb[8];
#pragma unroll
    for (int jj = 0; jj < 8; jj++) Fb[jj] = 0.f;

#pragma unroll
    for (int tap = 0; tap < KSIZE; tap++) {
      bool gm = mask_l && (pos - tap * dil >= 0) && (tjv[tap] != 0.f);
      float fv[8] = {fa[tap].x, fa[tap].y, fa[tap].z, fa[tap].w,
                     fbv[tap].x, fbv[tap].y, fbv[tap].z, fbv[tap].w};
      if (MODE == 0) {
        float zf = (tts[tap] != 0) ? 1.f : 0.f;
#pragma unroll
        for (int jj = 0; jj < 8; jj++) fv[jj] *= zf;
      } else {
#pragma unroll
        for (int jj = 0; jj < 8; jj++) {
          float x = fmaf(fv[jj], sc8[jj], ob8[jj]);
          fv[jj] = fmaxf(x, NEG * x);
        }
      }
      if (tap == 0) {
        float rv = rvalid ? 1.f : 0.f;
#pragma unroll
        for (int p2 = 0; p2 < 4; p2++) fself[p2] = mkh2(fv[2*p2] * rv, fv[2*p2+1] * rv);
      }
      float g = gm ? 1.f : 0.f;
#pragma unroll
      for (int jj = 0; jj < 8; jj++) Fb[jj] += g * fv[jj];
#pragma unroll
      for (int p2 = 0; p2 < 4; p2++) fh[tap][p2] = mkh2(fv[2*p2], fv[2*p2+1]);
    }

    // ---- phase M: 80 (row,tap) MLP jobs distributed over lanes ----
#pragma unroll
    for (int rep = 0; rep < 2; rep++) {
      const int jt = rep ? (KSIZE - 1) : (lane >> 4);
      const bool act = rep ? (lane < 16) : true;
      int j2 = pos - jt * dil;
      int jc2 = max(j2, 0);
      float tj2 = (jc2 == 0) ? 0.f : etimes[b * LIN + jc2 - 1];
      bool g2 = act && mask_l && (j2 >= 0) && (tj2 != 0.f);
      float dt = g2 ? (t_l - tj2) : 0.f;

      H8 w0, w1;
      if (__ballot(g2)) {
        const f4v* k1wv = (const f4v*)&sW[0];
        const f4v* k1bv = (const f4v*)&sW[16];
        const f4v* k2bv = (const f4v*)&sW[32];
        float h1[HCH], h2[HCH];
#pragma unroll
        for (int h4 = 0; h4 < 4; h4++) {
          f4v cw = k1wv[h4], cb = k1bv[h4], c2 = k2bv[h4];
#pragma unroll
          for (int r = 0; r < 4; r++) {
            float x = fmaf(dt, cw[r], cb[r]);
            h1[h4*4+r] = fmaxf(x, NEG * x);
            h2[h4*4+r] = c2[r];
          }
        }
#pragma unroll
        for (int hp = 0; hp < HCH; hp++) {
          float hv = h1[hp];
          const f4v* kk = (const f4v*)&sW[48 + hp * 16];
#pragma unroll
          for (int h4 = 0; h4 < 4; h4++) {
            f4v c = kk[h4];
#pragma unroll
            for (int r = 0; r < 4; r++) h2[h4*4+r] = fmaf(hv, c[r], h2[h4*4+r]);
          }
        }
        float g = g2 ? 1.f : 0.f;
#pragma unroll
        for (int p2 = 0; p2 < 4; p2++) {
          float a0 = h2[2*p2];     a0 = fmaxf(a0, NEG * a0) * g;
          float a1 = h2[2*p2+1];   a1 = fmaxf(a1, NEG * a1) * g;
          w0.h[p2] = mkh2(a0, a1);
          float b0 = h2[8+2*p2];   b0 = fmaxf(b0, NEG * b0) * g;
          float b1 = h2[8+2*p2+1]; b1 = fmaxf(b1, NEG * b1) * g;
          w1.h[p2] = mkh2(b0, b1);
        }
      } else {
#pragma unroll
        for (int p2 = 0; p2 < 4; p2++) { w0.h[p2] = mkh2(0.f, 0.f); w1.h[p2] = mkh2(0.f, 0.f); }
      }
      if (act) {
        int base = ((wv * KSIZE + jt) * 16 + m) * 2;
        swh[base] = w0.v; swh[base + 1] = w1.v;
      }
    }
    __syncthreads();   // (A)

    // ---- phase U: read wh, pack A-frags, MFMA ----
    h2v wh[KSIZE][8];
#pragma unroll
    for (int tap = 0; tap < KSIZE; tap++) {
      int base = ((wv * KSIZE + tap) * 16 + m) * 2;
      H8 a0, a1; a0.v = swh[base]; a1.v = swh[base + 1];
#pragma unroll
      for (int p2 = 0; p2 < 4; p2++) { wh[tap][p2] = a0.h[p2]; wh[tap][4+p2] = a1.h[p2]; }
    }

    f4v aP = {0,0,0,0}, aQ = {0,0,0,0}, bP = {0,0,0,0}, bQ = {0,0,0,0};

#pragma unroll
    for (int ks = 0; ks < 16; ks++) {
      H8 bf0, bf1, af;
      if (MODE == 0) {
        bf0.v = Wl[(2*ks + 0) * 64 + lane];
        bf1.v = Wl[(2*ks + 1) * 64 + lane];
      } else {
        bf0.v = *(const h8v*)(WtG + (size_t)((2*ks + 0) * 64 + lane) * 8);
        bf1.v = *(const h8v*)(WtG + (size_t)((2*ks + 1) * 64 + lane) * 8);
      }
      h2v u0 = mkh2(0.f,0.f), u1 = mkh2(0.f,0.f), u2 = mkh2(0.f,0.f), u3 = mkh2(0.f,0.f);
#pragma unroll
      for (int tap = 0; tap < KSIZE; tap++) {
        _Float16 w = wh[tap][ks >> 1][ks & 1];
        h2v wd; wd[0] = w; wd[1] = w;
        u0 += wd * fh[tap][0];
        u1 += wd * fh[tap][1];
        u2 += wd * fh[tap][2];
        u3 += wd * fh[tap][3];
      }
      af.h[0] = u0; af.h[1] = u1; af.h[2] = u2; af.h[3] = u3;
      if (ks & 1) {
        aQ = __builtin_amdgcn_mfma_f32_16x16x32_f16(af.v, bf0.v, aQ, 0, 0, 0);
        bQ = __builtin_amdgcn_mfma_f32_16x16x32_f16(af.v, bf1.v, bQ, 0, 0, 0);
      } else {
        aP = __builtin_amdgcn_mfma_f32_16x16x32_f16(af.v, bf0.v, aP, 0, 0, 0);
        bP = __builtin_amdgcn_mfma_f32_16x16x32_f16(af.v, bf1.v, bP, 0, 0, 0);
      }
    }
    { // k3b block (frags 32,33)
      H8 bf0, bf1, af;
      if (MODE == 0) { bf0.v = Wl[32 * 64 + lane]; bf1.v = Wl[33 * 64 + lane]; }
      else {
        bf0.v = *(const h8v*)(WtG + (size_t)(32 * 64 + lane) * 8);
        bf1.v = *(const h8v*)(WtG + (size_t)(33 * 64 + lane) * 8);
      }
#pragma unroll
      for (int p2 = 0; p2 < 4; p2++) af.h[p2] = mkh2(Fb[2*p2], Fb[2*p2+1]);
      aP = __builtin_amdgcn_mfma_f32_16x16x32_f16(af.v, bf0.v, aP, 0, 0, 0);
      bP = __builtin_amdgcn_mfma_f32_16x16x32_f16(af.v, bf1.v, bP, 0, 0, 0);
    }
    { // skip block (frags 34,35)
      H8 bf0, bf1, af;
      if (MODE == 0) { bf0.v = Wl[34 * 64 + lane]; bf1.v = Wl[35 * 64 + lane]; }
      else {
        bf0.v = *(const h8v*)(WtG + (size_t)(34 * 64 + lane) * 8);
        bf1.v = *(const h8v*)(WtG + (size_t)(35 * 64 + lane) * 8);
      }
      af.h[0] = fself[0]; af.h[1] = fself[1]; af.h[2] = fself[2]; af.h[3] = fself[3];
      aQ = __builtin_amdgcn_mfma_f32_16x16x32_f16(af.v, bf0.v, aQ, 0, 0, 0);
      bQ = __builtin_amdgcn_mfma_f32_16x16x32_f16(af.v, bf1.v, bQ, 0, 0, 0);
    }
    f4v acc0 = aP + aQ;
    f4v acc1 = bP + bQ;

    // epilogue: store + BN stats.  D layout: col = lane&15, row = (lane>>4)*4 + r
    float s0 = 0.f, s1 = 0.f, s2 = 0.f, s3 = 0.f;
#pragma unroll
    for (int r = 0; r < 4; r++) {
      float v0 = acc0[r], v1 = acc1[r];
      s0 += v0; s1 += v0 * v0; s2 += v1; s3 += v1 * v1;
      int rd = tile * 16 + q * 4 + r;
      if (rd < MROWS) {
        enc_out[rd * CCH + m] = v0;
        enc_out[rd * CCH + 16 + m] = v1;
      }
    }
    s0 += __shfl_xor(s0, 16, 64); s0 += __shfl_xor(s0, 32, 64);
    s1 += __shfl_xor(s1, 16, 64); s1 += __shfl_xor(s1, 32, 64);
    s2 += __shfl_xor(s2, 16, 64); s2 += __shfl_xor(s2, 32, 64);
    s3 += __shfl_xor(s3, 16, 64); s3 += __shfl_xor(s3, 32, 64);
    if (q == 0) {
      atomicAdd(&sst[m], s0);
      atomicAdd(&sst[32 + m], s1);
      atomicAdd(&sst[16 + m], s2);
      atomicAdd(&sst[48 + m], s3);
    }
  } else {
    __syncthreads();   // match (A) for dead-tile waves
  }
  __syncthreads();
  if (tid < 64) {
    if (MODE == 0) partials_out[blockIdx.x * 64 + tid] = sst[tid];
    else           atomicAdd(&stats_out[tid], sst[tid]);
  }
}

// ---------------- final BN + leaky-relu ----------------
// grid: 2049 x 256 (MROWS*CCH exactly)
__global__ __launch_bounds__(256) void bn_kernel(
    const float* __restrict__ x, float* __restrict__ out,
    const float* __restrict__ stats,
    const float* __restrict__ gamma, const float* __restrict__ beta) {
  int id = blockIdx.x * blockDim.x + threadIdx.x;
  int c = id & 31;
  const float inv = 1.f / (float)MROWS;
  float mu = stats[c] * inv;
  float var = stats[32 + c] * inv - mu * mu;
  float sc = gamma[c] * rsqrtf(var + BNEPS);
  float v = fmaf(x[id], sc, beta[c] - mu * sc);
  out[id] = fmaxf(v, NEG * v);
}

extern "C" void kernel_launch(void* const* d_in, const int* in_sizes, int n_in,
                              void* d_out, int out_size, void* d_ws, size_t ws_size,
                              hipStream_t stream) {
  (void)in_sizes; (void)n_in; (void)out_size; (void)ws_size;
  const float* event_times = (const float*)d_in[0];
  const int*   event_types = (const int*)d_in[1];
  const float* emb   = (const float*)d_in[2];
  const float* k1W   = (const float*)d_in[3];
  const float* k1b   = (const float*)d_in[4];
  const float* k2W   = (const float*)d_in[5];
  const float* k2b   = (const float*)d_in[6];
  const float* k3W   = (const float*)d_in[7];
  const float* k3b   = (const float*)d_in[8];
  const float* skipW = (const float*)d_in[9];
  // d_in[10] = skipb: BN-invariant, dropped
  const float* gamma = (const float*)d_in[11];
  const float* beta  = (const float*)d_in[12];

  float* enc_a = (float*)d_ws;
  float* enc_b = enc_a + (size_t)MROWS * CCH;
  float* stats = enc_b + (size_t)MROWS * CCH;          // [0..63] unused; [64..255] = stats of layers 1..3
  float* partials0 = stats + NB_LAYERS * 64;           // GRID*64 floats
  _Float16* WtG = (_Float16*)(((uintptr_t)(partials0 + GRID * 64) + 255) & ~(uintptr_t)255);

  // conv0: prep fused (LDS Wt build, global Wt for layers 1-3, stats zeroing, BOS scan,
  //        embedding fused), stats out as per-block partials
  conv_kernel<0><<<GRID, BLK, 0, stream>>>(
      nullptr, event_types, emb, enc_b, event_times,
      k1W, k1b, k2W, k2b, k3W, k3b, skipW, WtG,
      nullptr, nullptr, nullptr, partials0, stats + 64,
      nullptr, nullptr, 1);

  // conv1: reduce conv0 partials for BN; atomic stats into stats[1]
  conv_kernel<1><<<GRID, BLK, 0, stream>>>(
      enc_b, nullptr, nullptr, enc_a, event_times,
      k1W + HCH, k1b + HCH, k2W + HCH*HCH, k2b + HCH,
      nullptr, nullptr, nullptr, WtG + 0 * WT_HALVES,
      nullptr, partials0, stats + 64, nullptr, nullptr,
      gamma + 0 * CCH, beta + 0 * CCH, 2);

  // conv2
  conv_kernel<1><<<GRID, BLK, 0, stream>>>(
      enc_a, nullptr, nullptr, enc_b, event_times,
      k1W + 2*HCH, k1b + 2*HCH, k2W + 2*HCH*HCH, k2b + 2*HCH,
      nullptr, nullptr, nullptr, WtG + 1 * WT_HALVES,
      stats + 64, nullptr, stats + 128, nullptr, nullptr,
      gamma + 1 * CCH, beta + 1 * CCH, 4);

  // conv3
  conv_kernel<1><<<GRID, BLK, 0, stream>>>(
      enc_b, nullptr, nullptr, enc_a, event_times,
      k1W + 3*HCH, k1b + 3*HCH, k2W + 3*HCH*HCH, k2b + 3*HCH,
      nullptr, nullptr, nullptr, WtG + 2 * WT_HALVES,
      stats + 128, nullptr, stats + 192, nullptr, nullptr,
      gamma + 2 * CCH, beta + 2 * CCH, 8);

  // final BN+leaky of layer 3
  bn_kernel<<<2049, 256, 0, stream>>>(enc_a, (float*)d_out,
      stats + 192, gamma + 3 * CCH, beta + 3 * CCH);
}

// Round 7
// 152.736 us; speedup vs baseline: 1.8381x; 1.0979x over previous
//
#include <hip/hip_runtime.h>
#include <stdint.h>

#define NB_LAYERS 4
#define KSIZE 5
#define BSZ 8
#define LIN 2048
#define LSEQ 2049
#define CCH 32
#define HCH 16
#define MROWS (BSZ*LSEQ)          // 16392
#define NTILES ((MROWS+15)/16)    // 1025
#define KDIM 576                  // 512 (h*c) + 32 (k3b block) + 32 (skip block)
#define NEG 0.1f
#define BNEPS 1e-5f
#define CONVGRID 205
#define CONVBLK 320               // 5 waves * 205 blocks = 1025 waves = NTILES exactly

typedef _Float16 h2v __attribute__((ext_vector_type(2)));
typedef _Float16 h8v __attribute__((ext_vector_type(8)));
typedef float    f4v __attribute__((ext_vector_type(4)));

union H8 { h8v v; h2v h[4]; };

static __device__ __forceinline__ h2v mkh2(float a, float b) {
  h2v r; r[0] = (_Float16)a; r[1] = (_Float16)b; return r;
}

// ---------------- fused cont-conv layer ----------------
// MODE 0 (conv0): embedding fused into gathers; B-frags read RAW from fp32
//   k3W/k3b/skipW with on-the-fly fp16 cvt (no weight table dependency -> prep
//   kernel eliminated); builds the fp16 Wt table for layers 1-3 grid-wide
//   (1 elem/thread); zeroes stats[1..3] (block 0); inline BOS type-max scan;
//   BN stats out as per-block partials (no atomics, no pre-zero needed).
// MODE 1 (conv1-3): R3-verbatim — previous layer's BN+leaky fused into gathers
//   (conv1 reduces conv0's partials in prologue; conv2/3 read stats), B-frags
//   row-major from global fp16 Wt, stats via atomics into memory zeroed by conv0.
template<int MODE>
__global__ __launch_bounds__(CONVBLK) void conv_kernel(
    const float* __restrict__ enc_in,
    const int*   __restrict__ types,
    const float* __restrict__ emb,
    float* __restrict__ enc_out,
    const float* __restrict__ etimes,
    const float* __restrict__ k1Wp, const float* __restrict__ k1bp,
    const float* __restrict__ k2Wp, const float* __restrict__ k2bp,
    const float* __restrict__ k3W, const float* __restrict__ k3b,
    const float* __restrict__ skipW,
    _Float16* __restrict__ Wt,                // MODE0: write (layers 1-3); MODE1: this layer's slice (read)
    const float* __restrict__ stats_prev,     // conv2/3
    const float* __restrict__ partials_prev,  // conv1
    float* __restrict__ stats_out,            // conv1..3 atomic dest
    float* __restrict__ partials_out,         // conv0
    float* __restrict__ stats_zero,           // conv0: 192 floats (stats[1..3])
    const float* __restrict__ gamma_prev, const float* __restrict__ beta_prev,
    int dil)
{
  __shared__ h8v swh[(CONVBLK/64) * KSIZE * 16 * 2]; // per-wave MLP results
  __shared__ alignas(16) float sW[304];              // k1w[16] k1b[16] k2b[16] k2W[256]
  __shared__ float sst[64];
  __shared__ float sbn[64];

  const int tid  = threadIdx.x;
  const int lane = tid & 63;
  const int wv   = tid >> 6;
  const int m    = lane & 15;     // A-frag row within tile / B-frag col n
  const int q    = lane >> 4;     // quad: k-subchunk + feat channels q*8..q*8+7

  // ---- staging ----
  if (tid < 64) { sst[tid] = 0.f; sbn[tid] = 0.f; }
  if (tid < 16) { sW[tid] = k1Wp[tid]; sW[16 + tid] = k1bp[tid]; sW[32 + tid] = k2bp[tid]; }
  if (tid >= 64) sW[48 + tid - 64] = k2Wp[tid - 64];   // 256 entries, threads 64..319

  if (MODE == 0) {
    if (blockIdx.x == 0 && tid < 192) stats_zero[tid] = 0.f;
    // fp16 Wt tables for layers 1-3 (R3 prep body, grid-wide, 1 elem/thread)
    int id2 = blockIdx.x * CONVBLK + tid;              // 0..65599 >= 55296
    if (id2 < 3 * CCH * KDIM) {
      int layer = 1 + id2 / (CCH * KDIM);
      int rem = id2 % (CCH * KDIM);
      int n = rem / KDIM;
      int k = rem % KDIM;
      float val;
      if (k < 512)      { int h = k >> 5, c = k & 31; val = k3W[layer*16384 + h*1024 + c*32 + n]; }
      else if (k < 544) { int c = k - 512;            val = k3b[layer*1024 + c*32 + n]; }
      else              { int c = k - 544;            val = skipW[layer*1024 + c*32 + n]; }
      Wt[layer * (CCH * KDIM) + rem] = (_Float16)val;
    }
  }
  __syncthreads();

  // conv1 only: reduce conv0's per-block stat partials.
  // 320 % 64 == 0 -> each thread's channel (tid&63) is constant; 41 independent
  // coalesced loads per thread, 5-way LDS atomic depth per channel.
  if (MODE == 1 && partials_prev) {
    float v = 0.f;
#pragma unroll 8
    for (int i = tid; i < CONVGRID * 64; i += CONVBLK) v += partials_prev[i];
    atomicAdd(&sbn[tid & 63], v);
    __syncthreads();
  }

  // BN of previous layer, fused into loads: x -> leaky(x*sc + ob)
  float sc8[8], ob8[8];
  if (MODE == 1) {
    const float inv = 1.f / (float)MROWS;
#pragma unroll
    for (int j = 0; j < 8; j++) {
      int c = q * 8 + j;
      float s1 = partials_prev ? sbn[c]      : stats_prev[c];
      float s2 = partials_prev ? sbn[32 + c] : stats_prev[32 + c];
      float mu = s1 * inv;
      float var = s2 * inv - mu * mu;
      float sc = gamma_prev[c] * rsqrtf(var + BNEPS);
      sc8[j] = sc; ob8[j] = beta_prev[c] - mu * sc;
    }
  }

  const _Float16* wb0 = Wt + m * KDIM + q * 8;         // MODE1 only
  const _Float16* wb1 = Wt + (m + 16) * KDIM + q * 8;

  const int tile = blockIdx.x * (CONVBLK / 64) + wv;   // exactly one tile per wave, 1025 total
  int row = tile * 16 + m;
  bool rvalid = row < MROWS;
  int rowc = min(row, MROWS - 1);
  int b = rowc / LSEQ, pos = rowc % LSEQ;
  float t_l = (pos == 0) ? 0.f : etimes[b * LIN + pos - 1];
  bool mask_l = rvalid && (t_l != 0.f);

  // BOS embedding index: inline int4 scan (only the 8 waves containing a pos==0 row)
  int bosv = 0;
  if (MODE == 0) {
    if (__ballot(pos == 0)) {
      const int4* tp = (const int4*)types;
      int mx = 0;
#pragma unroll 4
      for (int i = lane; i < (BSZ * LIN) / 4; i += 64) {
        int4 v = tp[i];
        mx = max(mx, max(max(v.x, v.y), max(v.z, v.w)));
      }
#pragma unroll
      for (int off = 32; off; off >>= 1) mx = max(mx, __shfl_xor(mx, off, 64));
      bosv = mx + 1;
    }
  }

  // ---- phase G: prefetch all gather data, then transform ----
  int jcs[KSIZE]; float tjv[KSIZE];
#pragma unroll
  for (int tap = 0; tap < KSIZE; tap++) {
    int j = pos - tap * dil;
    int jc = max(j, 0); jcs[tap] = jc;
    tjv[tap] = (jc == 0) ? 0.f : etimes[b * LIN + jc - 1];
  }
  float4 fa[KSIZE], fbv[KSIZE];
  int tts[KSIZE];
  if (MODE == 0) {
#pragma unroll
    for (int tap = 0; tap < KSIZE; tap++) {
      int jc = jcs[tap];
      tts[tap] = (jc > 0) ? types[b * LIN + jc - 1] : ((tap == 0) ? bosv : 0);
    }
#pragma unroll
    for (int tap = 0; tap < KSIZE; tap++) {
      const float* ep = emb + tts[tap] * CCH + q * 8;
      fa[tap] = *(const float4*)ep; fbv[tap] = *(const float4*)(ep + 4);
    }
  } else {
#pragma unroll
    for (int tap = 0; tap < KSIZE; tap++) {
      const float* fp = enc_in + (b * LSEQ + jcs[tap]) * CCH + q * 8;
      fa[tap] = *(const float4*)fp; fbv[tap] = *(const float4*)(fp + 4);
    }
  }

  h2v fh[KSIZE][4];
  h2v fself[4];
  float Fb[8];
#pragma unroll
  for (int jj = 0; jj < 8; jj++) Fb[jj] = 0.f;

#pragma unroll
  for (int tap = 0; tap < KSIZE; tap++) {
    bool gm = mask_l && (pos - tap * dil >= 0) && (tjv[tap] != 0.f);
    float fv[8] = {fa[tap].x, fa[tap].y, fa[tap].z, fa[tap].w,
                   fbv[tap].x, fbv[tap].y, fbv[tap].z, fbv[tap].w};
    if (MODE == 0) {
      float zf = (tts[tap] != 0) ? 1.f : 0.f;
#pragma unroll
      for (int jj = 0; jj < 8; jj++) fv[jj] *= zf;
    } else {
#pragma unroll
      for (int jj = 0; jj < 8; jj++) {
        float x = fmaf(fv[jj], sc8[jj], ob8[jj]);
        fv[jj] = fmaxf(x, NEG * x);
      }
    }
    if (tap == 0) {
      float rv = rvalid ? 1.f : 0.f;
#pragma unroll
      for (int p2 = 0; p2 < 4; p2++) fself[p2] = mkh2(fv[2*p2] * rv, fv[2*p2+1] * rv);
    }
    float g = gm ? 1.f : 0.f;
#pragma unroll
    for (int jj = 0; jj < 8; jj++) Fb[jj] += g * fv[jj];
#pragma unroll
    for (int p2 = 0; p2 < 4; p2++) fh[tap][p2] = mkh2(fv[2*p2], fv[2*p2+1]);
  }

  // ---- phase M: 80 (row,tap) MLP jobs distributed over lanes ----
#pragma unroll
  for (int rep = 0; rep < 2; rep++) {
    const int jt = rep ? (KSIZE - 1) : (lane >> 4);
    const bool act = rep ? (lane < 16) : true;
    int j2 = pos - jt * dil;
    int jc2 = max(j2, 0);
    float tj2 = (jc2 == 0) ? 0.f : etimes[b * LIN + jc2 - 1];
    bool g2 = act && mask_l && (j2 >= 0) && (tj2 != 0.f);
    float dt = g2 ? (t_l - tj2) : 0.f;

    H8 w0, w1;
    if (__ballot(g2)) {
      const f4v* k1wv = (const f4v*)&sW[0];
      const f4v* k1bv = (const f4v*)&sW[16];
      const f4v* k2bv = (const f4v*)&sW[32];
      float h1[HCH], h2[HCH];
#pragma unroll
      for (int h4 = 0; h4 < 4; h4++) {
        f4v cw = k1wv[h4], cb = k1bv[h4], c2 = k2bv[h4];
#pragma unroll
        for (int r = 0; r < 4; r++) {
          float x = fmaf(dt, cw[r], cb[r]);
          h1[h4*4+r] = fmaxf(x, NEG * x);
          h2[h4*4+r] = c2[r];
        }
      }
#pragma unroll
      for (int hp = 0; hp < HCH; hp++) {
        float hv = h1[hp];
        const f4v* kk = (const f4v*)&sW[48 + hp * 16];
#pragma unroll
        for (int h4 = 0; h4 < 4; h4++) {
          f4v c = kk[h4];
#pragma unroll
          for (int r = 0; r < 4; r++) h2[h4*4+r] = fmaf(hv, c[r], h2[h4*4+r]);
        }
      }
      float g = g2 ? 1.f : 0.f;
#pragma unroll
      for (int p2 = 0; p2 < 4; p2++) {
        float a0 = h2[2*p2];     a0 = fmaxf(a0, NEG * a0) * g;
        float a1 = h2[2*p2+1];   a1 = fmaxf(a1, NEG * a1) * g;
        w0.h[p2] = mkh2(a0, a1);
        float b0 = h2[8+2*p2];   b0 = fmaxf(b0, NEG * b0) * g;
        float b1 = h2[8+2*p2+1]; b1 = fmaxf(b1, NEG * b1) * g;
        w1.h[p2] = mkh2(b0, b1);
      }
    } else {
#pragma unroll
      for (int p2 = 0; p2 < 4; p2++) { w0.h[p2] = mkh2(0.f, 0.f); w1.h[p2] = mkh2(0.f, 0.f); }
    }
    if (act) {
      int base = ((wv * KSIZE + jt) * 16 + m) * 2;
      swh[base] = w0.v; swh[base + 1] = w1.v;
    }
  }
  __syncthreads();

  // ---- phase U: read wh, pack A-frags, MFMA ----
  h2v wh[KSIZE][8];
#pragma unroll
  for (int tap = 0; tap < KSIZE; tap++) {
    int base = ((wv * KSIZE + tap) * 16 + m) * 2;
    H8 a0, a1; a0.v = swh[base]; a1.v = swh[base + 1];
#pragma unroll
    for (int p2 = 0; p2 < 4; p2++) { wh[tap][p2] = a0.h[p2]; wh[tap][4+p2] = a1.h[p2]; }
  }

  f4v aP = {0,0,0,0}, aQ = {0,0,0,0}, bP = {0,0,0,0}, bQ = {0,0,0,0};

#pragma unroll
  for (int ks = 0; ks < 16; ks++) {
    H8 bf0, bf1, af;
    if (MODE == 0) {
      // raw fp32 weights, fp16-convert on the fly (identical values to the table path):
      // half hh <- k3W[ks*1024 + (q*8+hh)*32 + n], n = m (bf0) / m+16 (bf1)
      const float* wp = k3W + ks * 1024 + (q * 8) * 32 + m;
#pragma unroll
      for (int p2 = 0; p2 < 4; p2++) {
        bf0.h[p2] = mkh2(wp[(2*p2) * 32],      wp[(2*p2+1) * 32]);
        bf1.h[p2] = mkh2(wp[(2*p2) * 32 + 16], wp[(2*p2+1) * 32 + 16]);
      }
    } else {
      bf0.v = *(const h8v*)(wb0 + ks * 32);
      bf1.v = *(const h8v*)(wb1 + ks * 32);
    }
    h2v u0 = mkh2(0.f,0.f), u1 = mkh2(0.f,0.f), u2 = mkh2(0.f,0.f), u3 = mkh2(0.f,0.f);
#pragma unroll
    for (int tap = 0; tap < KSIZE; tap++) {
      _Float16 w = wh[tap][ks >> 1][ks & 1];
      h2v wd; wd[0] = w; wd[1] = w;
      u0 += wd * fh[tap][0];
      u1 += wd * fh[tap][1];
      u2 += wd * fh[tap][2];
      u3 += wd * fh[tap][3];
    }
    af.h[0] = u0; af.h[1] = u1; af.h[2] = u2; af.h[3] = u3;
    if (ks & 1) {
      aQ = __builtin_amdgcn_mfma_f32_16x16x32_f16(af.v, bf0.v, aQ, 0, 0, 0);
      bQ = __builtin_amdgcn_mfma_f32_16x16x32_f16(af.v, bf1.v, bQ, 0, 0, 0);
    } else {
      aP = __builtin_amdgcn_mfma_f32_16x16x32_f16(af.v, bf0.v, aP, 0, 0, 0);
      bP = __builtin_amdgcn_mfma_f32_16x16x32_f16(af.v, bf1.v, bP, 0, 0, 0);
    }
  }
  { // k3b block (k = 512..543): val = k3b[c*32 + n], c = q*8+hh
    H8 bf0, bf1, af;
    if (MODE == 0) {
      const float* kp = k3b + (q * 8) * 32 + m;
#pragma unroll
      for (int p2 = 0; p2 < 4; p2++) {
        bf0.h[p2] = mkh2(kp[(2*p2) * 32],      kp[(2*p2+1) * 32]);
        bf1.h[p2] = mkh2(kp[(2*p2) * 32 + 16], kp[(2*p2+1) * 32 + 16]);
      }
    } else {
      bf0.v = *(const h8v*)(wb0 + 512);
      bf1.v = *(const h8v*)(wb1 + 512);
    }
#pragma unroll
    for (int p2 = 0; p2 < 4; p2++) af.h[p2] = mkh2(Fb[2*p2], Fb[2*p2+1]);
    aP = __builtin_amdgcn_mfma_f32_16x16x32_f16(af.v, bf0.v, aP, 0, 0, 0);
    bP = __builtin_amdgcn_mfma_f32_16x16x32_f16(af.v, bf1.v, bP, 0, 0, 0);
  }
  { // skip block (k = 544..575): val = skipW[c*32 + n]
    H8 bf0, bf1, af;
    if (MODE == 0) {
      const float* sp = skipW + (q * 8) * 32 + m;
#pragma unroll
      for (int p2 = 0; p2 < 4; p2++) {
        bf0.h[p2] = mkh2(sp[(2*p2) * 32],      sp[(2*p2+1) * 32]);
        bf1.h[p2] = mkh2(sp[(2*p2) * 32 + 16], sp[(2*p2+1) * 32 + 16]);
      }
    } else {
      bf0.v = *(const h8v*)(wb0 + 544);
      bf1.v = *(const h8v*)(wb1 + 544);
    }
    af.h[0] = fself[0]; af.h[1] = fself[1]; af.h[2] = fself[2]; af.h[3] = fself[3];
    aQ = __builtin_amdgcn_mfma_f32_16x16x32_f16(af.v, bf0.v, aQ, 0, 0, 0);
    bQ = __builtin_amdgcn_mfma_f32_16x16x32_f16(af.v, bf1.v, bQ, 0, 0, 0);
  }
  f4v acc0 = aP + aQ;
  f4v acc1 = bP + bQ;

  // epilogue: store + BN stats.  D layout: col = lane&15, row = (lane>>4)*4 + r
  float s0 = 0.f, s1 = 0.f, s2 = 0.f, s3 = 0.f;
#pragma unroll
  for (int r = 0; r < 4; r++) {
    float v0 = acc0[r], v1 = acc1[r];
    s0 += v0; s1 += v0 * v0; s2 += v1; s3 += v1 * v1;
    int rd = tile * 16 + q * 4 + r;
    if (rd < MROWS) {
      enc_out[rd * CCH + m] = v0;
      enc_out[rd * CCH + 16 + m] = v1;
    }
  }
  s0 += __shfl_xor(s0, 16, 64); s0 += __shfl_xor(s0, 32, 64);
  s1 += __shfl_xor(s1, 16, 64); s1 += __shfl_xor(s1, 32, 64);
  s2 += __shfl_xor(s2, 16, 64); s2 += __shfl_xor(s2, 32, 64);
  s3 += __shfl_xor(s3, 16, 64); s3 += __shfl_xor(s3, 32, 64);
  if (q == 0) {
    atomicAdd(&sst[m], s0);
    atomicAdd(&sst[32 + m], s1);
    atomicAdd(&sst[16 + m], s2);
    atomicAdd(&sst[48 + m], s3);
  }
  __syncthreads();
  if (tid < 64) {
    if (MODE == 0) partials_out[blockIdx.x * 64 + tid] = sst[tid];
    else           atomicAdd(&stats_out[tid], sst[tid]);
  }
}

// ---------------- final BN + leaky-relu ----------------
// grid: 2049 x 256 (MROWS*CCH exactly)
__global__ __launch_bounds__(256) void bn_kernel(
    const float* __restrict__ x, float* __restrict__ out,
    const float* __restrict__ stats,
    const float* __restrict__ gamma, const float* __restrict__ beta) {
  int id = blockIdx.x * blockDim.x + threadIdx.x;
  int c = id & 31;
  const float inv = 1.f / (float)MROWS;
  float mu = stats[c] * inv;
  float var = stats[32 + c] * inv - mu * mu;
  float sc = gamma[c] * rsqrtf(var + BNEPS);
  float v = fmaf(x[id], sc, beta[c] - mu * sc);
  out[id] = fmaxf(v, NEG * v);
}

extern "C" void kernel_launch(void* const* d_in, const int* in_sizes, int n_in,
                              void* d_out, int out_size, void* d_ws, size_t ws_size,
                              hipStream_t stream) {
  (void)in_sizes; (void)n_in; (void)out_size; (void)ws_size;
  const float* event_times = (const float*)d_in[0];
  const int*   event_types = (const int*)d_in[1];
  const float* emb   = (const float*)d_in[2];
  const float* k1W   = (const float*)d_in[3];
  const float* k1b   = (const float*)d_in[4];
  const float* k2W   = (const float*)d_in[5];
  const float* k2b   = (const float*)d_in[6];
  const float* k3W   = (const float*)d_in[7];
  const float* k3b   = (const float*)d_in[8];
  const float* skipW = (const float*)d_in[9];
  // d_in[10] = skipb: BN-invariant, dropped
  const float* gamma = (const float*)d_in[11];
  const float* beta  = (const float*)d_in[12];

  float* enc_a = (float*)d_ws;
  float* enc_b = enc_a + (size_t)MROWS * CCH;
  float* stats = enc_b + (size_t)MROWS * CCH;          // [0..63] unused; [64..255] = layers 1..3
  float* partials0 = stats + NB_LAYERS * 64;           // CONVGRID*64 floats
  _Float16* Wt = (_Float16*)(((uintptr_t)(partials0 + CONVGRID * 64) + 255) & ~(uintptr_t)255);

  // conv0: raw-weight B-frags (no table dep), builds Wt for layers 1-3, zeroes
  //        stats[1..3], inline BOS scan, embedding fused, stats as per-block partials
  conv_kernel<0><<<CONVGRID, CONVBLK, 0, stream>>>(
      nullptr, event_types, emb, enc_b, event_times,
      k1W, k1b, k2W, k2b, k3W, k3b, skipW, Wt,
      nullptr, nullptr, nullptr, partials0, stats + 64,
      nullptr, nullptr, 1);

  // conv1: reduce conv0 partials for BN; atomic stats into stats[1]
  conv_kernel<1><<<CONVGRID, CONVBLK, 0, stream>>>(
      enc_b, nullptr, nullptr, enc_a, event_times,
      k1W + HCH, k1b + HCH, k2W + HCH*HCH, k2b + HCH,
      nullptr, nullptr, nullptr, Wt + 1 * CCH * KDIM,
      nullptr, partials0, stats + 64, nullptr, nullptr,
      gamma + 0 * CCH, beta + 0 * CCH, 2);

  // conv2
  conv_kernel<1><<<CONVGRID, CONVBLK, 0, stream>>>(
      enc_a, nullptr, nullptr, enc_b, event_times,
      k1W + 2*HCH, k1b + 2*HCH, k2W + 2*HCH*HCH, k2b + 2*HCH,
      nullptr, nullptr, nullptr, Wt + 2 * CCH * KDIM,
      stats + 64, nullptr, stats + 128, nullptr, nullptr,
      gamma + 1 * CCH, beta + 1 * CCH, 4);

  // conv3
  conv_kernel<1><<<CONVGRID, CONVBLK, 0, stream>>>(
      enc_b, nullptr, nullptr, enc_a, event_times,
      k1W + 3*HCH, k1b + 3*HCH, k2W + 3*HCH*HCH, k2b + 3*HCH,
      nullptr, nullptr, nullptr, Wt + 3 * CCH * KDIM,
      stats + 128, nullptr, stats + 192, nullptr, nullptr,
      gamma + 2 * CCH, beta + 2 * CCH, 8);

  // final BN+leaky of layer 3
  bn_kernel<<<2049, 256, 0, stream>>>(enc_a, (float*)d_out,
      stats + 192, gamma + 3 * CCH, beta + 3 * CCH);
}

// Round 8
// 149.876 us; speedup vs baseline: 1.8732x; 1.0191x over previous
//
#include <hip/hip_runtime.h>
#include <stdint.h>

#define NB_LAYERS 4
#define KSIZE 5
#define BSZ 8
#define LIN 2048
#define LSEQ 2049
#define CCH 32
#define HCH 16
#define MROWS (BSZ*LSEQ)          // 16392
#define NTILES ((MROWS+15)/16)    // 1025
#define NEG 0.1f
#define BNEPS 1e-5f
#define CONVGRID 129              // 129 blocks * 8 waves = 1032 tiles (1025 real, 7 dead)
#define CONVBLK 512               // 8 waves -> 2 waves/SIMD: latency hiding via TLP
#define NFRAG 36                  // 32 K-frags + 2 k3b + 2 skip
#define WT_HALVES (NFRAG*64*8)    // 18432 fp16 per layer

typedef _Float16 h2v __attribute__((ext_vector_type(2)));
typedef _Float16 h8v __attribute__((ext_vector_type(8)));
typedef float    f4v __attribute__((ext_vector_type(4)));

union H8 { h8v v; h2v h[4]; };

static __device__ __forceinline__ h2v mkh2(float a, float b) {
  h2v r; r[0] = (_Float16)a; r[1] = (_Float16)b; return r;
}

// decode one source element of a layer's weight table -> (dest half-index, value)
// source linear g: [0,16384) k3W slice, [16384,17408) k3b, [17408,18432) skipW
// dest layout: frag f (0..35) * 512 + lane(q<<4|m) * 8 + half(0..7)
// -> B-frag reads are lane-consecutive 16B chunks (coalesced).  (verified R4/R6)
static __device__ __forceinline__ void wt_decode(
    int g, const float* __restrict__ k3Wl, const float* __restrict__ k3bl,
    const float* __restrict__ skipWl, int& halfidx, float& val) {
  int n, k;
  if (g < 16384)      { n = g & 31; int c = (g >> 5) & 31; int h = g >> 10; k = h * 32 + c; val = k3Wl[g]; }
  else if (g < 17408) { int g2 = g - 16384; n = g2 & 31; int c = g2 >> 5; k = 512 + c; val = k3bl[g2]; }
  else                { int g2 = g - 17408; n = g2 & 31; int c = g2 >> 5; k = 544 + c; val = skipWl[g2]; }
  int m = n & 15, a = n >> 4, qq = (k >> 3) & 3, hh = k & 7;
  int f = (k < 512) ? ((k >> 5) * 2 + a) : ((k < 544) ? (32 + a) : (34 + a));
  halfidx = f * 512 + ((qq << 4) | m) * 8 + hh;
}

// ---------------- fused cont-conv layer ----------------
// MODE 0 (conv0): embedding fused into gathers; B-frags read RAW from fp32
//   k3W/k3b/skipW with on-the-fly fp16 cvt; builds frag-linear fp16 Wt for
//   layers 1-3 grid-wide (1 elem/thread); zeroes stats[1..3] (block 0); inline
//   BOS type-max scan; BN stats out as per-block partials.
// MODE 1 (conv1-3): previous layer's BN+leaky fused into gathers (conv1 reduces
//   conv0's partials; conv2/3 read stats), B-frags frag-linear from global fp16
//   Wt (lane-consecutive 16B = coalesced), stats via atomics.
template<int MODE>
__global__ __launch_bounds__(CONVBLK) void conv_kernel(
    const float* __restrict__ enc_in,
    const int*   __restrict__ types,
    const float* __restrict__ emb,
    float* __restrict__ enc_out,
    const float* __restrict__ etimes,
    const float* __restrict__ k1Wp, const float* __restrict__ k1bp,
    const float* __restrict__ k2Wp, const float* __restrict__ k2bp,
    const float* __restrict__ k3W, const float* __restrict__ k3b,
    const float* __restrict__ skipW,
    _Float16* __restrict__ Wt,                // MODE0: write base (layers 1-3); MODE1: this layer's slice (read)
    const float* __restrict__ stats_prev,     // conv2/3
    const float* __restrict__ partials_prev,  // conv1
    float* __restrict__ stats_out,            // conv1..3 atomic dest
    float* __restrict__ partials_out,         // conv0
    float* __restrict__ stats_zero,           // conv0: 192 floats (stats[1..3])
    const float* __restrict__ gamma_prev, const float* __restrict__ beta_prev,
    int dil)
{
  __shared__ h8v swh[(CONVBLK/64) * KSIZE * 16 * 2]; // per-wave MLP results (20 KB)
  __shared__ alignas(16) float sW[304];              // k1w[16] k1b[16] k2b[16] k2W[256]
  __shared__ float sst[64];
  __shared__ float sbn[64];

  const int tid  = threadIdx.x;
  const int lane = tid & 63;
  const int wv   = tid >> 6;
  const int m    = lane & 15;     // A-frag row within tile / B-frag col n
  const int q    = lane >> 4;     // quad: k-subchunk + feat channels q*8..q*8+7

  // ---- staging ----
  if (tid < 64) { sst[tid] = 0.f; sbn[tid] = 0.f; }
  if (tid < 16) { sW[tid] = k1Wp[tid]; sW[16 + tid] = k1bp[tid]; sW[32 + tid] = k2bp[tid]; }
  if (tid >= 64 && tid < 320) sW[48 + tid - 64] = k2Wp[tid - 64];

  if (MODE == 0) {
    if (blockIdx.x == 0 && tid < 192) stats_zero[tid] = 0.f;
    // frag-linear fp16 Wt for layers 1-3: one element per thread grid-wide
    int id2 = blockIdx.x * CONVBLK + tid;              // 0..66047 >= 55296
    if (id2 < 3 * WT_HALVES) {
      int layer = 1 + id2 / WT_HALVES;
      int g = id2 - (layer - 1) * WT_HALVES;
      int hi; float val;
      wt_decode(g, k3W + layer * 16384, k3b + layer * 1024, skipW + layer * 1024, hi, val);
      Wt[(layer - 1) * WT_HALVES + hi] = (_Float16)val;
    }
  }
  __syncthreads();

  // conv1 only: reduce conv0's per-block stat partials (channel = tid&63 constant)
  if (MODE == 1 && partials_prev) {
    float v = 0.f;
#pragma unroll 4
    for (int i = tid; i < CONVGRID * 64; i += CONVBLK) v += partials_prev[i];
    atomicAdd(&sbn[tid & 63], v);
    __syncthreads();
  }

  // BN of previous layer, fused into loads: x -> leaky(x*sc + ob)
  float sc8[8], ob8[8];
  if (MODE == 1) {
    const float inv = 1.f / (float)MROWS;
#pragma unroll
    for (int j = 0; j < 8; j++) {
      int c = q * 8 + j;
      float s1 = partials_prev ? sbn[c]      : stats_prev[c];
      float s2 = partials_prev ? sbn[32 + c] : stats_prev[32 + c];
      float mu = s1 * inv;
      float var = s2 * inv - mu * mu;
      float sc = gamma_prev[c] * rsqrtf(var + BNEPS);
      sc8[j] = sc; ob8[j] = beta_prev[c] - mu * sc;
    }
  }

  const int tile = blockIdx.x * (CONVBLK / 64) + wv;   // one tile per wave
  const bool deadtile = (tile >= NTILES);              // tiles 1025..1031: fully dead

  if (!deadtile) {
    int row = tile * 16 + m;
    bool rvalid = row < MROWS;
    int rowc = min(row, MROWS - 1);
    int b = rowc / LSEQ, pos = rowc % LSEQ;
    float t_l = (pos == 0) ? 0.f : etimes[b * LIN + pos - 1];
    bool mask_l = rvalid && (t_l != 0.f);

    // BOS embedding index: inline int4 scan (only the 8 waves containing a pos==0 row)
    int bosv = 0;
    if (MODE == 0) {
      if (__ballot(pos == 0)) {
        const int4* tp = (const int4*)types;
        int mx = 0;
#pragma unroll 4
        for (int i = lane; i < (BSZ * LIN) / 4; i += 64) {
          int4 v = tp[i];
          mx = max(mx, max(max(v.x, v.y), max(v.z, v.w)));
        }
#pragma unroll
        for (int off = 32; off; off >>= 1) mx = max(mx, __shfl_xor(mx, off, 64));
        bosv = mx + 1;
      }
    }

    // ---- phase G: prefetch all gather data, then transform ----
    int jcs[KSIZE]; float tjv[KSIZE];
#pragma unroll
    for (int tap = 0; tap < KSIZE; tap++) {
      int j = pos - tap * dil;
      int jc = max(j, 0); jcs[tap] = jc;
      tjv[tap] = (jc == 0) ? 0.f : etimes[b * LIN + jc - 1];
    }
    float4 fa[KSIZE], fbv[KSIZE];
    int tts[KSIZE];
    if (MODE == 0) {
#pragma unroll
      for (int tap = 0; tap < KSIZE; tap++) {
        int jc = jcs[tap];
        tts[tap] = (jc > 0) ? types[b * LIN + jc - 1] : ((tap == 0) ? bosv : 0);
      }
#pragma unroll
      for (int tap = 0; tap < KSIZE; tap++) {
        const float* ep = emb + tts[tap] * CCH + q * 8;
        fa[tap] = *(const float4*)ep; fbv[tap] = *(const float4*)(ep + 4);
      }
    } else {
#pragma unroll
      for (int tap = 0; tap < KSIZE; tap++) {
        const float* fp = enc_in + (b * LSEQ + jcs[tap]) * CCH + q * 8;
        fa[tap] = *(const float4*)fp; fbv[tap] = *(const float4*)(fp + 4);
      }
    }

    h2v fh[KSIZE][4];
    h2v fself[4];
    float Fb[8];
#pragma unroll
    for (int jj = 0; jj < 8; jj++) Fb[jj] = 0.f;

#pragma unroll
    for (int tap = 0; tap < KSIZE; tap++) {
      bool gm = mask_l && (pos - tap * dil >= 0) && (tjv[tap] != 0.f);
      float fv[8] = {fa[tap].x, fa[tap].y, fa[tap].z, fa[tap].w,
                     fbv[tap].x, fbv[tap].y, fbv[tap].z, fbv[tap].w};
      if (MODE == 0) {
        float zf = (tts[tap] != 0) ? 1.f : 0.f;
#pragma unroll
        for (int jj = 0; jj < 8; jj++) fv[jj] *= zf;
      } else {
#pragma unroll
        for (int jj = 0; jj < 8; jj++) {
          float x = fmaf(fv[jj], sc8[jj], ob8[jj]);
          fv[jj] = fmaxf(x, NEG * x);
        }
      }
      if (tap == 0) {
        float rv = rvalid ? 1.f : 0.f;
#pragma unroll
        for (int p2 = 0; p2 < 4; p2++) fself[p2] = mkh2(fv[2*p2] * rv, fv[2*p2+1] * rv);
      }
      float g = gm ? 1.f : 0.f;
#pragma unroll
      for (int jj = 0; jj < 8; jj++) Fb[jj] += g * fv[jj];
#pragma unroll
      for (int p2 = 0; p2 < 4; p2++) fh[tap][p2] = mkh2(fv[2*p2], fv[2*p2+1]);
    }

    // ---- phase M: 80 (row,tap) MLP jobs distributed over lanes ----
#pragma unroll
    for (int rep = 0; rep < 2; rep++) {
      const int jt = rep ? (KSIZE - 1) : (lane >> 4);
      const bool act = rep ? (lane < 16) : true;
      int j2 = pos - jt * dil;
      int jc2 = max(j2, 0);
      float tj2 = (jc2 == 0) ? 0.f : etimes[b * LIN + jc2 - 1];
      bool g2 = act && mask_l && (j2 >= 0) && (tj2 != 0.f);
      float dt = g2 ? (t_l - tj2) : 0.f;

      H8 w0, w1;
      if (__ballot(g2)) {
        const f4v* k1wv = (const f4v*)&sW[0];
        const f4v* k1bv = (const f4v*)&sW[16];
        const f4v* k2bv = (const f4v*)&sW[32];
        float h1[HCH], h2[HCH];
#pragma unroll
        for (int h4 = 0; h4 < 4; h4++) {
          f4v cw = k1wv[h4], cb = k1bv[h4], c2 = k2bv[h4];
#pragma unroll
          for (int r = 0; r < 4; r++) {
            float x = fmaf(dt, cw[r], cb[r]);
            h1[h4*4+r] = fmaxf(x, NEG * x);
            h2[h4*4+r] = c2[r];
          }
        }
#pragma unroll
        for (int hp = 0; hp < HCH; hp++) {
          float hv = h1[hp];
          const f4v* kk = (const f4v*)&sW[48 + hp * 16];
#pragma unroll
          for (int h4 = 0; h4 < 4; h4++) {
            f4v c = kk[h4];
#pragma unroll
            for (int r = 0; r < 4; r++) h2[h4*4+r] = fmaf(hv, c[r], h2[h4*4+r]);
          }
        }
        float g = g2 ? 1.f : 0.f;
#pragma unroll
        for (int p2 = 0; p2 < 4; p2++) {
          float a0 = h2[2*p2];     a0 = fmaxf(a0, NEG * a0) * g;
          float a1 = h2[2*p2+1];   a1 = fmaxf(a1, NEG * a1) * g;
          w0.h[p2] = mkh2(a0, a1);
          float b0 = h2[8+2*p2];   b0 = fmaxf(b0, NEG * b0) * g;
          float b1 = h2[8+2*p2+1]; b1 = fmaxf(b1, NEG * b1) * g;
          w1.h[p2] = mkh2(b0, b1);
        }
      } else {
#pragma unroll
        for (int p2 = 0; p2 < 4; p2++) { w0.h[p2] = mkh2(0.f, 0.f); w1.h[p2] = mkh2(0.f, 0.f); }
      }
      if (act) {
        int base = ((wv * KSIZE + jt) * 16 + m) * 2;
        swh[base] = w0.v; swh[base + 1] = w1.v;
      }
    }
    __syncthreads();   // (A)

    // ---- phase U: read wh, pack A-frags, MFMA ----
    h2v wh[KSIZE][8];
#pragma unroll
    for (int tap = 0; tap < KSIZE; tap++) {
      int base = ((wv * KSIZE + tap) * 16 + m) * 2;
      H8 a0, a1; a0.v = swh[base]; a1.v = swh[base + 1];
#pragma unroll
      for (int p2 = 0; p2 < 4; p2++) { wh[tap][p2] = a0.h[p2]; wh[tap][4+p2] = a1.h[p2]; }
    }

    f4v aP = {0,0,0,0}, aQ = {0,0,0,0}, bP = {0,0,0,0}, bQ = {0,0,0,0};

#pragma unroll
    for (int ks = 0; ks < 16; ks++) {
      H8 bf0, bf1, af;
      if (MODE == 0) {
        // raw fp32 weights, fp16-convert on the fly (identical values to table path)
        const float* wp = k3W + ks * 1024 + (q * 8) * 32 + m;
#pragma unroll
        for (int p2 = 0; p2 < 4; p2++) {
          bf0.h[p2] = mkh2(wp[(2*p2) * 32],      wp[(2*p2+1) * 32]);
          bf1.h[p2] = mkh2(wp[(2*p2) * 32 + 16], wp[(2*p2+1) * 32 + 16]);
        }
      } else {
        bf0.v = *(const h8v*)(Wt + (size_t)((2*ks + 0) * 64 + lane) * 8);
        bf1.v = *(const h8v*)(Wt + (size_t)((2*ks + 1) * 64 + lane) * 8);
      }
      h2v u0 = mkh2(0.f,0.f), u1 = mkh2(0.f,0.f), u2 = mkh2(0.f,0.f), u3 = mkh2(0.f,0.f);
#pragma unroll
      for (int tap = 0; tap < KSIZE; tap++) {
        _Float16 w = wh[tap][ks >> 1][ks & 1];
        h2v wd; wd[0] = w; wd[1] = w;
        u0 += wd * fh[tap][0];
        u1 += wd * fh[tap][1];
        u2 += wd * fh[tap][2];
        u3 += wd * fh[tap][3];
      }
      af.h[0] = u0; af.h[1] = u1; af.h[2] = u2; af.h[3] = u3;
      if (ks & 1) {
        aQ = __builtin_amdgcn_mfma_f32_16x16x32_f16(af.v, bf0.v, aQ, 0, 0, 0);
        bQ = __builtin_amdgcn_mfma_f32_16x16x32_f16(af.v, bf1.v, bQ, 0, 0, 0);
      } else {
        aP = __builtin_amdgcn_mfma_f32_16x16x32_f16(af.v, bf0.v, aP, 0, 0, 0);
        bP = __builtin_amdgcn_mfma_f32_16x16x32_f16(af.v, bf1.v, bP, 0, 0, 0);
      }
    }
    { // k3b block (frags 32,33)
      H8 bf0, bf1, af;
      if (MODE == 0) {
        const float* kp = k3b + (q * 8) * 32 + m;
#pragma unroll
        for (int p2 = 0; p2 < 4; p2++) {
          bf0.h[p2] = mkh2(kp[(2*p2) * 32],      kp[(2*p2+1) * 32]);
          bf1.h[p2] = mkh2(kp[(2*p2) * 32 + 16], kp[(2*p2+1) * 32 + 16]);
        }
      } else {
        bf0.v = *(const h8v*)(Wt + (size_t)(32 * 64 + lane) * 8);
        bf1.v = *(const h8v*)(Wt + (size_t)(33 * 64 + lane) * 8);
      }
#pragma unroll
      for (int p2 = 0; p2 < 4; p2++) af.h[p2] = mkh2(Fb[2*p2], Fb[2*p2+1]);
      aP = __builtin_amdgcn_mfma_f32_16x16x32_f16(af.v, bf0.v, aP, 0, 0, 0);
      bP = __builtin_amdgcn_mfma_f32_16x16x32_f16(af.v, bf1.v, bP, 0, 0, 0);
    }
    { // skip block (frags 34,35)
      H8 bf0, bf1, af;
      if (MODE == 0) {
        const float* sp = skipW + (q * 8) * 32 + m;
#pragma unroll
        for (int p2 = 0; p2 < 4; p2++) {
          bf0.h[p2] = mkh2(sp[(2*p2) * 32],      sp[(2*p2+1) * 32]);
          bf1.h[p2] = mkh2(sp[(2*p2) * 32 + 16], sp[(2*p2+1) * 32 + 16]);
        }
      } else {
        bf0.v = *(const h8v*)(Wt + (size_t)(34 * 64 + lane) * 8);
        bf1.v = *(const h8v*)(Wt + (size_t)(35 * 64 + lane) * 8);
      }
      af.h[0] = fself[0]; af.h[1] = fself[1]; af.h[2] = fself[2]; af.h[3] = fself[3];
      aQ = __builtin_amdgcn_mfma_f32_16x16x32_f16(af.v, bf0.v, aQ, 0, 0, 0);
      bQ = __builtin_amdgcn_mfma_f32_16x16x32_f16(af.v, bf1.v, bQ, 0, 0, 0);
    }
    f4v acc0 = aP + aQ;
    f4v acc1 = bP + bQ;

    // epilogue: store + BN stats.  D layout: col = lane&15, row = (lane>>4)*4 + r
    float s0 = 0.f, s1 = 0.f, s2 = 0.f, s3 = 0.f;
#pragma unroll
    for (int r = 0; r < 4; r++) {
      float v0 = acc0[r], v1 = acc1[r];
      s0 += v0; s1 += v0 * v0; s2 += v1; s3 += v1 * v1;
      int rd = tile * 16 + q * 4 + r;
      if (rd < MROWS) {
        enc_out[rd * CCH + m] = v0;
        enc_out[rd * CCH + 16 + m] = v1;
      }
    }
    s0 += __shfl_xor(s0, 16, 64); s0 += __shfl_xor(s0, 32, 64);
    s1 += __shfl_xor(s1, 16, 64); s1 += __shfl_xor(s1, 32, 64);
    s2 += __shfl_xor(s2, 16, 64); s2 += __shfl_xor(s2, 32, 64);
    s3 += __shfl_xor(s3, 16, 64); s3 += __shfl_xor(s3, 32, 64);
    if (q == 0) {
      atomicAdd(&sst[m], s0);
      atomicAdd(&sst[32 + m], s1);
      atomicAdd(&sst[16 + m], s2);
      atomicAdd(&sst[48 + m], s3);
    }
  } else {
    __syncthreads();   // match (A) for dead-tile waves
  }
  __syncthreads();
  if (tid < 64) {
    if (MODE == 0) partials_out[blockIdx.x * 64 + tid] = sst[tid];
    else           atomicAdd(&stats_out[tid], sst[tid]);
  }
}

// ---------------- final BN + leaky-relu ----------------
// grid: 256 x 256, float4 grid-stride (MROWS*CCH/4 = 131136 float4s)
__global__ __launch_bounds__(256) void bn_kernel(
    const float* __restrict__ x, float* __restrict__ out,
    const float* __restrict__ stats,
    const float* __restrict__ gamma, const float* __restrict__ beta) {
  int idx0 = blockIdx.x * 256 + threadIdx.x;
  // stride*4 % 32 == 0 -> this thread's 4 channels are constant across iterations
  int c0 = (idx0 * 4) & 31;
  const float inv = 1.f / (float)MROWS;
  float sc[4], ob[4];
#pragma unroll
  for (int r = 0; r < 4; r++) {
    int c = c0 + r;
    float mu = stats[c] * inv;
    float var = stats[32 + c] * inv - mu * mu;
    sc[r] = gamma[c] * rsqrtf(var + BNEPS);
    ob[r] = beta[c] - mu * sc[r];
  }
  for (int i = idx0; i < (MROWS * CCH) / 4; i += 256 * 256) {
    float4 v = ((const float4*)x)[i];
    float4 o;
    o.x = fmaf(v.x, sc[0], ob[0]); o.x = fmaxf(o.x, NEG * o.x);
    o.y = fmaf(v.y, sc[1], ob[1]); o.y = fmaxf(o.y, NEG * o.y);
    o.z = fmaf(v.z, sc[2], ob[2]); o.z = fmaxf(o.z, NEG * o.z);
    o.w = fmaf(v.w, sc[3], ob[3]); o.w = fmaxf(o.w, NEG * o.w);
    ((float4*)out)[i] = o;
  }
}

extern "C" void kernel_launch(void* const* d_in, const int* in_sizes, int n_in,
                              void* d_out, int out_size, void* d_ws, size_t ws_size,
                              hipStream_t stream) {
  (void)in_sizes; (void)n_in; (void)out_size; (void)ws_size;
  const float* event_times = (const float*)d_in[0];
  const int*   event_types = (const int*)d_in[1];
  const float* emb   = (const float*)d_in[2];
  const float* k1W   = (const float*)d_in[3];
  const float* k1b   = (const float*)d_in[4];
  const float* k2W   = (const float*)d_in[5];
  const float* k2b   = (const float*)d_in[6];
  const float* k3W   = (const float*)d_in[7];
  const float* k3b   = (const float*)d_in[8];
  const float* skipW = (const float*)d_in[9];
  // d_in[10] = skipb: BN-invariant, dropped
  const float* gamma = (const float*)d_in[11];
  const float* beta  = (const float*)d_in[12];

  float* enc_a = (float*)d_ws;
  float* enc_b = enc_a + (size_t)MROWS * CCH;
  float* stats = enc_b + (size_t)MROWS * CCH;          // [0..63] unused; [64..255] = layers 1..3
  float* partials0 = stats + NB_LAYERS * 64;           // CONVGRID*64 floats
  _Float16* Wt = (_Float16*)(((uintptr_t)(partials0 + CONVGRID * 64) + 255) & ~(uintptr_t)255);

  // conv0: raw-weight B-frags, builds frag-linear Wt for layers 1-3, zeroes
  //        stats[1..3], inline BOS scan, embedding fused, stats as per-block partials
  conv_kernel<0><<<CONVGRID, CONVBLK, 0, stream>>>(
      nullptr, event_types, emb, enc_b, event_times,
      k1W, k1b, k2W, k2b, k3W, k3b, skipW, Wt,
      nullptr, nullptr, nullptr, partials0, stats + 64,
      nullptr, nullptr, 1);

  // conv1: reduce conv0 partials for BN; atomic stats into stats[1]
  conv_kernel<1><<<CONVGRID, CONVBLK, 0, stream>>>(
      enc_b, nullptr, nullptr, enc_a, event_times,
      k1W + HCH, k1b + HCH, k2W + HCH*HCH, k2b + HCH,
      nullptr, nullptr, nullptr, Wt + 0 * WT_HALVES,
      nullptr, partials0, stats + 64, nullptr, nullptr,
      gamma + 0 * CCH, beta + 0 * CCH, 2);

  // conv2
  conv_kernel<1><<<CONVGRID, CONVBLK, 0, stream>>>(
      enc_a, nullptr, nullptr, enc_b, event_times,
      k1W + 2*HCH, k1b + 2*HCH, k2W + 2*HCH*HCH, k2b + 2*HCH,
      nullptr, nullptr, nullptr, Wt + 1 * WT_HALVES,
      stats + 64, nullptr, stats + 128, nullptr, nullptr,
      gamma + 1 * CCH, beta + 1 * CCH, 4);

  // conv3
  conv_kernel<1><<<CONVGRID, CONVBLK, 0, stream>>>(
      enc_b, nullptr, nullptr, enc_a, event_times,
      k1W + 3*HCH, k1b + 3*HCH, k2W + 3*HCH*HCH, k2b + 3*HCH,
      nullptr, nullptr, nullptr, Wt + 2 * WT_HALVES,
      stats + 128, nullptr, stats + 192, nullptr, nullptr,
      gamma + 2 * CCH, beta + 2 * CCH, 8);

  // final BN+leaky of layer 3
  bn_kernel<<<256, 256, 0, stream>>>(enc_a, (float*)d_out,
      stats + 192, gamma + 3 * CCH, beta + 3 * CCH);
}

// Round 9
// 143.929 us; speedup vs baseline: 1.9506x; 1.0413x over previous
//
#include <hip/hip_runtime.h>
#include <stdint.h>

#define NB_LAYERS 4
#define KSIZE 5
#define BSZ 8
#define LIN 2048
#define LSEQ 2049
#define CCH 32
#define HCH 16
#define MROWS (BSZ*LSEQ)          // 16392
#define NTILES ((MROWS+15)/16)    // 1025
#define NEG 0.1f
#define BNEPS 1e-5f
#define CONVGRID 129              // 129 blocks * 8 waves = 1032 tiles (1025 real, 7 dead)
#define CONVBLK 512               // 8 waves -> 2 waves/SIMD
#define NWAVES (CONVBLK/64)
#define NJOBS (NWAVES*KSIZE*16)   // 640 MLP jobs per block
#define NFRAG 36                  // 32 K-frags + 2 k3b + 2 skip
#define WT_HALVES (NFRAG*64*8)    // 18432 fp16 per layer

typedef _Float16 h2v __attribute__((ext_vector_type(2)));
typedef _Float16 h8v __attribute__((ext_vector_type(8)));
typedef float    f4v __attribute__((ext_vector_type(4)));

union H8 { h8v v; h2v h[4]; };

static __device__ __forceinline__ h2v mkh2(float a, float b) {
  h2v r; r[0] = (_Float16)a; r[1] = (_Float16)b; return r;
}

// decode one source element of a layer's weight table -> (dest half-index, value)
// dest layout: frag f (0..35) * 512 + lane(q<<4|m) * 8 + half(0..7) — lane-consecutive 16B
static __device__ __forceinline__ void wt_decode(
    int g, const float* __restrict__ k3Wl, const float* __restrict__ k3bl,
    const float* __restrict__ skipWl, int& halfidx, float& val) {
  int n, k;
  if (g < 16384)      { n = g & 31; int c = (g >> 5) & 31; int h = g >> 10; k = h * 32 + c; val = k3Wl[g]; }
  else if (g < 17408) { int g2 = g - 16384; n = g2 & 31; int c = g2 >> 5; k = 512 + c; val = k3bl[g2]; }
  else                { int g2 = g - 17408; n = g2 & 31; int c = g2 >> 5; k = 544 + c; val = skipWl[g2]; }
  int m = n & 15, a = n >> 4, qq = (k >> 3) & 3, hh = k & 7;
  int f = (k < 512) ? ((k >> 5) * 2 + a) : ((k < 544) ? (32 + a) : (34 + a));
  halfidx = f * 512 + ((qq << 4) | m) * 8 + hh;
}

// ---------------- fused cont-conv layer ----------------
// MODE 0 (conv0): embedding fused; B-frags raw from fp32 (coalesced strided loads);
//   builds frag-linear fp16 Wt for layers 1-3 grid-wide; zeroes stats[1..3];
//   inline BOS scan; stats out as per-block partials.
// MODE 1 (conv1-3): prev layer's BN+leaky fused into gathers; Wt staged to LDS via
//   LINEAR 36KB copy, B-frags = ds_read_b128; stats via atomics.
// MLP: block-cooperative — 640 jobs over 512 threads; rep0 = 1 job/thread,
//   rep1 (128 jobs) on waves 0-1 only (waves 2-7 ballot-skip).
template<int MODE>
__global__ __launch_bounds__(CONVBLK) void conv_kernel(
    const float* __restrict__ enc_in,
    const int*   __restrict__ types,
    const float* __restrict__ emb,
    float* __restrict__ enc_out,
    const float* __restrict__ etimes,
    const float* __restrict__ k1Wp, const float* __restrict__ k1bp,
    const float* __restrict__ k2Wp, const float* __restrict__ k2bp,
    const float* __restrict__ k3W, const float* __restrict__ k3b,
    const float* __restrict__ skipW,
    _Float16* __restrict__ WtG,               // MODE0: write base (layers 1-3); MODE1: this layer's slice (read)
    const float* __restrict__ stats_prev,     // conv2/3
    const float* __restrict__ partials_prev,  // conv1
    float* __restrict__ stats_out,            // conv1..3 atomic dest
    float* __restrict__ partials_out,         // conv0
    float* __restrict__ stats_zero,           // conv0: 192 floats (stats[1..3])
    const float* __restrict__ gamma_prev, const float* __restrict__ beta_prev,
    int dil)
{
  __shared__ h8v Wl[(MODE == 1) ? (NFRAG * 64) : 1];  // 36 KB LDS weight table (conv1-3)
  __shared__ h8v swh[NWAVES * KSIZE * 16 * 2];        // MLP results (20 KB)
  __shared__ alignas(16) float sW[304];               // k1w[16] k1b[16] k2b[16] k2W[256]
  __shared__ float sst[64];
  __shared__ float sbn[64];

  const int tid  = threadIdx.x;
  const int lane = tid & 63;
  const int wv   = tid >> 6;
  const int m    = lane & 15;     // A-frag row within tile / B-frag col n
  const int q    = lane >> 4;     // quad: k-subchunk + feat channels q*8..q*8+7
  const int bid  = blockIdx.x;

  // ---- staging ----
  if (tid < 64) { sst[tid] = 0.f; sbn[tid] = 0.f; }
  if (tid < 16) { sW[tid] = k1Wp[tid]; sW[16 + tid] = k1bp[tid]; sW[32 + tid] = k2bp[tid]; }
  if (tid >= 64 && tid < 320) sW[48 + tid - 64] = k2Wp[tid - 64];

  if (MODE == 0) {
    if (bid == 0 && tid < 192) stats_zero[tid] = 0.f;
    // frag-linear fp16 Wt for layers 1-3: one element per thread grid-wide
    int id2 = bid * CONVBLK + tid;                     // 0..66047 >= 55296
    if (id2 < 3 * WT_HALVES) {
      int layer = 1 + id2 / WT_HALVES;
      int g = id2 - (layer - 1) * WT_HALVES;
      int hi; float val;
      wt_decode(g, k3W + layer * 16384, k3b + layer * 1024, skipW + layer * 1024, hi, val);
      WtG[(layer - 1) * WT_HALVES + hi] = (_Float16)val;
    }
  } else {
    // linear 36KB copy: global frag-linear fp16 -> LDS (coalesced, conflict-free)
    const float4* src = (const float4*)WtG;
    float4* dst = (float4*)Wl;
#pragma unroll
    for (int i = 0; i < 5; i++) {
      int idx = tid + i * CONVBLK;
      if (idx < WT_HALVES / 8) dst[idx] = src[idx];
    }
  }
  __syncthreads();

  // conv1 only: reduce conv0's per-block stat partials (channel = tid&63 constant)
  if (MODE == 1 && partials_prev) {
    float v = 0.f;
#pragma unroll 4
    for (int i = tid; i < CONVGRID * 64; i += CONVBLK) v += partials_prev[i];
    atomicAdd(&sbn[tid & 63], v);
    __syncthreads();
  }

  // BN of previous layer, fused into loads: x -> leaky(x*sc + ob)
  float sc8[8], ob8[8];
  if (MODE == 1) {
    const float inv = 1.f / (float)MROWS;
#pragma unroll
    for (int j = 0; j < 8; j++) {
      int c = q * 8 + j;
      float s1 = partials_prev ? sbn[c]      : stats_prev[c];
      float s2 = partials_prev ? sbn[32 + c] : stats_prev[32 + c];
      float mu = s1 * inv;
      float var = s2 * inv - mu * mu;
      float sc = gamma_prev[c] * rsqrtf(var + BNEPS);
      sc8[j] = sc; ob8[j] = beta_prev[c] - mu * sc;
    }
  }

  const int tile = bid * NWAVES + wv;                  // one tile per wave
  const bool deadtile = (tile >= NTILES);              // tiles 1025..1031

  int row = tile * 16 + m;
  bool rvalid = row < MROWS;
  int rowc = min(row, MROWS - 1);
  int b = rowc / LSEQ, pos = rowc % LSEQ;
  float t_l = (pos == 0) ? 0.f : etimes[b * LIN + pos - 1];
  bool mask_l = rvalid && (t_l != 0.f);

  // ---- gather prefetch (issued before MLP so L2 latency hides under it) ----
  float4 fa[KSIZE], fbv[KSIZE];
  int tts[KSIZE];
  int jcs[KSIZE]; float tjv[KSIZE];
  if (!deadtile) {
    // BOS embedding index (conv0, only the 8 waves containing a pos==0 row)
    int bosv = 0;
    if (MODE == 0) {
      if (__ballot(pos == 0)) {
        const int4* tp = (const int4*)types;
        int mx = 0;
#pragma unroll 4
        for (int i = lane; i < (BSZ * LIN) / 4; i += 64) {
          int4 v = tp[i];
          mx = max(mx, max(max(v.x, v.y), max(v.z, v.w)));
        }
#pragma unroll
        for (int off = 32; off; off >>= 1) mx = max(mx, __shfl_xor(mx, off, 64));
        bosv = mx + 1;
      }
    }
#pragma unroll
    for (int tap = 0; tap < KSIZE; tap++) {
      int j = pos - tap * dil;
      int jc = max(j, 0); jcs[tap] = jc;
      tjv[tap] = (jc == 0) ? 0.f : etimes[b * LIN + jc - 1];
    }
    if (MODE == 0) {
#pragma unroll
      for (int tap = 0; tap < KSIZE; tap++) {
        int jc = jcs[tap];
        tts[tap] = (jc > 0) ? types[b * LIN + jc - 1] : ((tap == 0) ? bosv : 0);
      }
#pragma unroll
      for (int tap = 0; tap < KSIZE; tap++) {
        const float* ep = emb + tts[tap] * CCH + q * 8;
        fa[tap] = *(const float4*)ep; fbv[tap] = *(const float4*)(ep + 4);
      }
    } else {
#pragma unroll
      for (int tap = 0; tap < KSIZE; tap++) {
        const float* fp = enc_in + (b * LSEQ + jcs[tap]) * CCH + q * 8;
        fa[tap] = *(const float4*)fp; fbv[tap] = *(const float4*)(fp + 4);
      }
    }
  }

  // ---- MLP phase: block-cooperative, 640 jobs over 512 threads ----
  // rep 0: job = tid (512 jobs); rep 1: job = 512 + tid for tid < 128 (waves 0-1).
#pragma unroll
  for (int rep = 0; rep < 2; rep++) {
    const int job = rep ? (512 + tid) : tid;
    const bool act = rep ? (tid < 128) : true;
    const int jj2 = act ? job : 0;
    const int wvt = jj2 / 80;
    const int rr  = jj2 % 80;
    const int tap = rr / 16;
    const int jrow = rr % 16;
    const int tile_t = bid * NWAVES + wvt;
    int row_t = tile_t * 16 + jrow;
    bool rvalid_t = row_t < MROWS;
    int rowc_t = min(row_t, MROWS - 1);
    int b_t = rowc_t / LSEQ, pos_t = rowc_t % LSEQ;
    float tl_t = (pos_t == 0) ? 0.f : etimes[b_t * LIN + pos_t - 1];
    int j2 = pos_t - tap * dil;
    int jc2 = max(j2, 0);
    float tj2 = (jc2 == 0) ? 0.f : etimes[b_t * LIN + jc2 - 1];
    bool g2 = act && rvalid_t && (tl_t != 0.f) && (j2 >= 0) && (tj2 != 0.f);
    float dt = g2 ? (tl_t - tj2) : 0.f;

    H8 w0, w1;
    if (__ballot(g2)) {
      const f4v* k1wv = (const f4v*)&sW[0];
      const f4v* k1bv = (const f4v*)&sW[16];
      const f4v* k2bv = (const f4v*)&sW[32];
      float h1[HCH], h2[HCH];
#pragma unroll
      for (int h4 = 0; h4 < 4; h4++) {
        f4v cw = k1wv[h4], cb = k1bv[h4], c2 = k2bv[h4];
#pragma unroll
        for (int r = 0; r < 4; r++) {
          float x = fmaf(dt, cw[r], cb[r]);
          h1[h4*4+r] = fmaxf(x, NEG * x);
          h2[h4*4+r] = c2[r];
        }
      }
#pragma unroll
      for (int hp = 0; hp < HCH; hp++) {
        float hv = h1[hp];
        const f4v* kk = (const f4v*)&sW[48 + hp * 16];
#pragma unroll
        for (int h4 = 0; h4 < 4; h4++) {
          f4v c = kk[h4];
#pragma unroll
          for (int r = 0; r < 4; r++) h2[h4*4+r] = fmaf(hv, c[r], h2[h4*4+r]);
        }
      }
      float g = g2 ? 1.f : 0.f;
#pragma unroll
      for (int p2 = 0; p2 < 4; p2++) {
        float a0 = h2[2*p2];     a0 = fmaxf(a0, NEG * a0) * g;
        float a1 = h2[2*p2+1];   a1 = fmaxf(a1, NEG * a1) * g;
        w0.h[p2] = mkh2(a0, a1);
        float b0 = h2[8+2*p2];   b0 = fmaxf(b0, NEG * b0) * g;
        float b1 = h2[8+2*p2+1]; b1 = fmaxf(b1, NEG * b1) * g;
        w1.h[p2] = mkh2(b0, b1);
      }
    } else {
#pragma unroll
      for (int p2 = 0; p2 < 4; p2++) { w0.h[p2] = mkh2(0.f, 0.f); w1.h[p2] = mkh2(0.f, 0.f); }
    }
    if (act) {
      int base = ((wvt * KSIZE + tap) * 16 + jrow) * 2;
      swh[base] = w0.v; swh[base + 1] = w1.v;
    }
  }

  // ---- gather transform (loads have landed during MLP) ----
  h2v fh[KSIZE][4];
  h2v fself[4];
  float Fb[8];
  if (!deadtile) {
#pragma unroll
    for (int jj = 0; jj < 8; jj++) Fb[jj] = 0.f;
#pragma unroll
    for (int tap = 0; tap < KSIZE; tap++) {
      bool gm = mask_l && (pos - tap * dil >= 0) && (tjv[tap] != 0.f);
      float fv[8] = {fa[tap].x, fa[tap].y, fa[tap].z, fa[tap].w,
                     fbv[tap].x, fbv[tap].y, fbv[tap].z, fbv[tap].w};
      if (MODE == 0) {
        float zf = (tts[tap] != 0) ? 1.f : 0.f;
#pragma unroll
        for (int jj = 0; jj < 8; jj++) fv[jj] *= zf;
      } else {
#pragma unroll
        for (int jj = 0; jj < 8; jj++) {
          float x = fmaf(fv[jj], sc8[jj], ob8[jj]);
          fv[jj] = fmaxf(x, NEG * x);
        }
      }
      if (tap == 0) {
        float rv = rvalid ? 1.f : 0.f;
#pragma unroll
        for (int p2 = 0; p2 < 4; p2++) fself[p2] = mkh2(fv[2*p2] * rv, fv[2*p2+1] * rv);
      }
      float g = gm ? 1.f : 0.f;
#pragma unroll
      for (int jj = 0; jj < 8; jj++) Fb[jj] += g * fv[jj];
#pragma unroll
      for (int p2 = 0; p2 < 4; p2++) fh[tap][p2] = mkh2(fv[2*p2], fv[2*p2+1]);
    }
  }
  __syncthreads();   // MLP results visible block-wide

  if (!deadtile) {
    // ---- phase U: read wh, pack A-frags, MFMA ----
    h2v wh[KSIZE][8];
#pragma unroll
    for (int tap = 0; tap < KSIZE; tap++) {
      int base = ((wv * KSIZE + tap) * 16 + m) * 2;
      H8 a0, a1; a0.v = swh[base]; a1.v = swh[base + 1];
#pragma unroll
      for (int p2 = 0; p2 < 4; p2++) { wh[tap][p2] = a0.h[p2]; wh[tap][4+p2] = a1.h[p2]; }
    }

    f4v aP = {0,0,0,0}, aQ = {0,0,0,0}, bP = {0,0,0,0}, bQ = {0,0,0,0};

#pragma unroll
    for (int ks = 0; ks < 16; ks++) {
      H8 bf0, bf1, af;
      if (MODE == 0) {
        const float* wp = k3W + ks * 1024 + (q * 8) * 32 + m;
#pragma unroll
        for (int p2 = 0; p2 < 4; p2++) {
          bf0.h[p2] = mkh2(wp[(2*p2) * 32],      wp[(2*p2+1) * 32]);
          bf1.h[p2] = mkh2(wp[(2*p2) * 32 + 16], wp[(2*p2+1) * 32 + 16]);
        }
      } else {
        bf0.v = Wl[(2*ks + 0) * 64 + lane];
        bf1.v = Wl[(2*ks + 1) * 64 + lane];
      }
      h2v u0 = mkh2(0.f,0.f), u1 = mkh2(0.f,0.f), u2 = mkh2(0.f,0.f), u3 = mkh2(0.f,0.f);
#pragma unroll
      for (int tap = 0; tap < KSIZE; tap++) {
        _Float16 w = wh[tap][ks >> 1][ks & 1];
        h2v wd; wd[0] = w; wd[1] = w;
        u0 += wd * fh[tap][0];
        u1 += wd * fh[tap][1];
        u2 += wd * fh[tap][2];
        u3 += wd * fh[tap][3];
      }
      af.h[0] = u0; af.h[1] = u1; af.h[2] = u2; af.h[3] = u3;
      if (ks & 1) {
        aQ = __builtin_amdgcn_mfma_f32_16x16x32_f16(af.v, bf0.v, aQ, 0, 0, 0);
        bQ = __builtin_amdgcn_mfma_f32_16x16x32_f16(af.v, bf1.v, bQ, 0, 0, 0);
      } else {
        aP = __builtin_amdgcn_mfma_f32_16x16x32_f16(af.v, bf0.v, aP, 0, 0, 0);
        bP = __builtin_amdgcn_mfma_f32_16x16x32_f16(af.v, bf1.v, bP, 0, 0, 0);
      }
    }
    { // k3b block (frags 32,33)
      H8 bf0, bf1, af;
      if (MODE == 0) {
        const float* kp = k3b + (q * 8) * 32 + m;
#pragma unroll
        for (int p2 = 0; p2 < 4; p2++) {
          bf0.h[p2] = mkh2(kp[(2*p2) * 32],      kp[(2*p2+1) * 32]);
          bf1.h[p2] = mkh2(kp[(2*p2) * 32 + 16], kp[(2*p2+1) * 32 + 16]);
        }
      } else {
        bf0.v = Wl[32 * 64 + lane];
        bf1.v = Wl[33 * 64 + lane];
      }
#pragma unroll
      for (int p2 = 0; p2 < 4; p2++) af.h[p2] = mkh2(Fb[2*p2], Fb[2*p2+1]);
      aP = __builtin_amdgcn_mfma_f32_16x16x32_f16(af.v, bf0.v, aP, 0, 0, 0);
      bP = __builtin_amdgcn_mfma_f32_16x16x32_f16(af.v, bf1.v, bP, 0, 0, 0);
    }
    { // skip block (frags 34,35)
      H8 bf0, bf1, af;
      if (MODE == 0) {
        const float* sp = skipW + (q * 8) * 32 + m;
#pragma unroll
        for (int p2 = 0; p2 < 4; p2++) {
          bf0.h[p2] = mkh2(sp[(2*p2) * 32],      sp[(2*p2+1) * 32]);
          bf1.h[p2] = mkh2(sp[(2*p2) * 32 + 16], sp[(2*p2+1) * 32 + 16]);
        }
      } else {
        bf0.v = Wl[34 * 64 + lane];
        bf1.v = Wl[35 * 64 + lane];
      }
      af.h[0] = fself[0]; af.h[1] = fself[1]; af.h[2] = fself[2]; af.h[3] = fself[3];
      aQ = __builtin_amdgcn_mfma_f32_16x16x32_f16(af.v, bf0.v, aQ, 0, 0, 0);
      bQ = __builtin_amdgcn_mfma_f32_16x16x32_f16(af.v, bf1.v, bQ, 0, 0, 0);
    }
    f4v acc0 = aP + aQ;
    f4v acc1 = bP + bQ;

    // epilogue: store + BN stats.  D layout: col = lane&15, row = (lane>>4)*4 + r
    float s0 = 0.f, s1 = 0.f, s2 = 0.f, s3 = 0.f;
#pragma unroll
    for (int r = 0; r < 4; r++) {
      float v0 = acc0[r], v1 = acc1[r];
      s0 += v0; s1 += v0 * v0; s2 += v1; s3 += v1 * v1;
      int rd = tile * 16 + q * 4 + r;
      if (rd < MROWS) {
        enc_out[rd * CCH + m] = v0;
        enc_out[rd * CCH + 16 + m] = v1;
      }
    }
    s0 += __shfl_xor(s0, 16, 64); s0 += __shfl_xor(s0, 32, 64);
    s1 += __shfl_xor(s1, 16, 64); s1 += __shfl_xor(s1, 32, 64);
    s2 += __shfl_xor(s2, 16, 64); s2 += __shfl_xor(s2, 32, 64);
    s3 += __shfl_xor(s3, 16, 64); s3 += __shfl_xor(s3, 32, 64);
    if (q == 0) {
      atomicAdd(&sst[m], s0);
      atomicAdd(&sst[32 + m], s1);
      atomicAdd(&sst[16 + m], s2);
      atomicAdd(&sst[48 + m], s3);
    }
  }
  __syncthreads();
  if (tid < 64) {
    if (MODE == 0) partials_out[bid * 64 + tid] = sst[tid];
    else           atomicAdd(&stats_out[tid], sst[tid]);
  }
}

// ---------------- final BN + leaky-relu ----------------
// grid: 256 x 256, float4 grid-stride
__global__ __launch_bounds__(256) void bn_kernel(
    const float* __restrict__ x, float* __restrict__ out,
    const float* __restrict__ stats,
    const float* __restrict__ gamma, const float* __restrict__ beta) {
  int idx0 = blockIdx.x * 256 + threadIdx.x;
  int c0 = (idx0 * 4) & 31;
  const float inv = 1.f / (float)MROWS;
  float sc[4], ob[4];
#pragma unroll
  for (int r = 0; r < 4; r++) {
    int c = c0 + r;
    float mu = stats[c] * inv;
    float var = stats[32 + c] * inv - mu * mu;
    sc[r] = gamma[c] * rsqrtf(var + BNEPS);
    ob[r] = beta[c] - mu * sc[r];
  }
  for (int i = idx0; i < (MROWS * CCH) / 4; i += 256 * 256) {
    float4 v = ((const float4*)x)[i];
    float4 o;
    o.x = fmaf(v.x, sc[0], ob[0]); o.x = fmaxf(o.x, NEG * o.x);
    o.y = fmaf(v.y, sc[1], ob[1]); o.y = fmaxf(o.y, NEG * o.y);
    o.z = fmaf(v.z, sc[2], ob[2]); o.z = fmaxf(o.z, NEG * o.z);
    o.w = fmaf(v.w, sc[3], ob[3]); o.w = fmaxf(o.w, NEG * o.w);
    ((float4*)out)[i] = o;
  }
}

extern "C" void kernel_launch(void* const* d_in, const int* in_sizes, int n_in,
                              void* d_out, int out_size, void* d_ws, size_t ws_size,
                              hipStream_t stream) {
  (void)in_sizes; (void)n_in; (void)out_size; (void)ws_size;
  const float* event_times = (const float*)d_in[0];
  const int*   event_types = (const int*)d_in[1];
  const float* emb   = (const float*)d_in[2];
  const float* k1W   = (const float*)d_in[3];
  const float* k1b   = (const float*)d_in[4];
  const float* k2W   = (const float*)d_in[5];
  const float* k2b   = (const float*)d_in[6];
  const float* k3W   = (const float*)d_in[7];
  const float* k3b   = (const float*)d_in[8];
  const float* skipW = (const float*)d_in[9];
  // d_in[10] = skipb: BN-invariant, dropped
  const float* gamma = (const float*)d_in[11];
  const float* beta  = (const float*)d_in[12];

  float* enc_a = (float*)d_ws;
  float* enc_b = enc_a + (size_t)MROWS * CCH;
  float* stats = enc_b + (size_t)MROWS * CCH;          // [0..63] unused; [64..255] = layers 1..3
  float* partials0 = stats + NB_LAYERS * 64;           // CONVGRID*64 floats
  _Float16* Wt = (_Float16*)(((uintptr_t)(partials0 + CONVGRID * 64) + 255) & ~(uintptr_t)255);

  // conv0: raw-weight B-frags, builds frag-linear Wt for layers 1-3, zeroes
  //        stats[1..3], inline BOS scan, embedding fused, stats as per-block partials
  conv_kernel<0><<<CONVGRID, CONVBLK, 0, stream>>>(
      nullptr, event_types, emb, enc_b, event_times,
      k1W, k1b, k2W, k2b, k3W, k3b, skipW, Wt,
      nullptr, nullptr, nullptr, partials0, stats + 64,
      nullptr, nullptr, 1);

  // conv1: reduce conv0 partials for BN; atomic stats into stats[1]
  conv_kernel<1><<<CONVGRID, CONVBLK, 0, stream>>>(
      enc_b, nullptr, nullptr, enc_a, event_times,
      k1W + HCH, k1b + HCH, k2W + HCH*HCH, k2b + HCH,
      nullptr, nullptr, nullptr, Wt + 0 * WT_HALVES,
      nullptr, partials0, stats + 64, nullptr, nullptr,
      gamma + 0 * CCH, beta + 0 * CCH, 2);

  // conv2
  conv_kernel<1><<<CONVGRID, CONVBLK, 0, stream>>>(
      enc_a, nullptr, nullptr, enc_b, event_times,
      k1W + 2*HCH, k1b + 2*HCH, k2W + 2*HCH*HCH, k2b + 2*HCH,
      nullptr, nullptr, nullptr, Wt + 1 * WT_HALVES,
      stats + 64, nullptr, stats + 128, nullptr, nullptr,
      gamma + 1 * CCH, beta + 1 * CCH, 4);

  // conv3
  conv_kernel<1><<<CONVGRID, CONVBLK, 0, stream>>>(
      enc_b, nullptr, nullptr, enc_a, event_times,
      k1W + 3*HCH, k1b + 3*HCH, k2W + 3*HCH*HCH, k2b + 3*HCH,
      nullptr, nullptr, nullptr, Wt + 2 * WT_HALVES,
      stats + 128, nullptr, stats + 192, nullptr, nullptr,
      gamma + 2 * CCH, beta + 2 * CCH, 8);

  // final BN+leaky of layer 3
  bn_kernel<<<256, 256, 0, stream>>>(enc_a, (float*)d_out,
      stats + 192, gamma + 3 * CCH, beta + 3 * CCH);
}